// Round 1
// baseline (621.628 us; speedup 1.0000x reference)
//
#include <hip/hip_runtime.h>
#include <hip/hip_bf16.h>
#include <math.h>

#define N_NODES 50000
#define N_EDGESX 800000
#define E_TOT   (N_EDGESX + N_NODES)
#define IN_C 128
#define HID_C 256
#define OUT_C 128
#define NEG_SLOPE 0.2f

// ---------------- CSR build ----------------
__global__ void count_kernel(const int* __restrict__ dst, int* __restrict__ cnt) {
    int i = blockIdx.x * blockDim.x + threadIdx.x;
    if (i < E_TOT) {
        int d = (i < N_EDGESX) ? dst[i] : (i - N_EDGESX);
        atomicAdd(&cnt[d], 1);
    }
}

__global__ __launch_bounds__(1024)
void scan_kernel(int* __restrict__ cnt_and_cursor, int* __restrict__ row_ptr) {
    __shared__ int buf[1024];
    __shared__ int carry_s;
    int tid = threadIdx.x;
    if (tid == 0) carry_s = 0;
    __syncthreads();
    for (int base = 0; base < N_NODES; base += 1024) {
        int idx = base + tid;
        int v = (idx < N_NODES) ? cnt_and_cursor[idx] : 0;
        buf[tid] = v;
        __syncthreads();
        for (int off = 1; off < 1024; off <<= 1) {
            int t = (tid >= off) ? buf[tid - off] : 0;
            __syncthreads();
            buf[tid] += t;
            __syncthreads();
        }
        int incl = buf[tid];
        int carry = carry_s;
        if (idx < N_NODES) {
            int excl = carry + incl - v;
            row_ptr[idx] = excl;
            cnt_and_cursor[idx] = excl;   // becomes the scatter cursor
        }
        __syncthreads();
        if (tid == 1023) carry_s = carry + incl;
        __syncthreads();
    }
    if (tid == 0) row_ptr[N_NODES] = carry_s;
}

__global__ void scatter_kernel(const int* __restrict__ src, const int* __restrict__ dst,
                               int* __restrict__ cursor, int* __restrict__ esrc) {
    int i = blockIdx.x * blockDim.x + threadIdx.x;
    if (i < E_TOT) {
        int s, d;
        if (i < N_EDGESX) { s = src[i]; d = dst[i]; }
        else { s = i - N_EDGESX; d = s; }
        int pos = atomicAdd(&cursor[d], 1);
        esrc[pos] = s;
    }
}

// ---------------- fp32 tiled GEMM: C[M,N] = A[M,K] @ B[K,N] ----------------
// K, N multiples of 64. Grid: (N/64, ceil(M/64)), 256 threads.
__global__ __launch_bounds__(256)
void gemm64(const float* __restrict__ A, const float* __restrict__ B, float* __restrict__ C,
            int M, int N, int K) {
    __shared__ float As[64][68];   // [m][k], padded
    __shared__ float Bs[64][64];   // [k][n]
    int tid = threadIdx.x;
    int bm = blockIdx.y * 64;
    int bn = blockIdx.x * 64;
    int tx = tid & 15, ty = tid >> 4;
    int lr = tid >> 4;             // 0..15
    int lc4 = (tid & 15) * 4;      // 0,4,...,60
    float acc[4][4] = {};
    for (int k0 = 0; k0 < K; k0 += 64) {
        #pragma unroll
        for (int r = 0; r < 4; ++r) {
            int m = lr + 16 * r;
            int gm = bm + m;
            float4 v = make_float4(0.f, 0.f, 0.f, 0.f);
            if (gm < M) v = *reinterpret_cast<const float4*>(&A[(size_t)gm * K + k0 + lc4]);
            *reinterpret_cast<float4*>(&As[m][lc4]) = v;
        }
        #pragma unroll
        for (int r = 0; r < 4; ++r) {
            int kk = lr + 16 * r;
            float4 v = *reinterpret_cast<const float4*>(&B[(size_t)(k0 + kk) * N + bn + lc4]);
            *reinterpret_cast<float4*>(&Bs[kk][lc4]) = v;
        }
        __syncthreads();
        #pragma unroll 16
        for (int kk = 0; kk < 64; ++kk) {
            float a[4];
            #pragma unroll
            for (int i = 0; i < 4; ++i) a[i] = As[ty * 4 + i][kk];
            float4 b = *reinterpret_cast<const float4*>(&Bs[kk][tx * 4]);
            #pragma unroll
            for (int i = 0; i < 4; ++i) {
                acc[i][0] += a[i] * b.x;
                acc[i][1] += a[i] * b.y;
                acc[i][2] += a[i] * b.z;
                acc[i][3] += a[i] * b.w;
            }
        }
        __syncthreads();
    }
    #pragma unroll
    for (int i = 0; i < 4; ++i) {
        int gm = bm + ty * 4 + i;
        if (gm < M) {
            float4 v = make_float4(acc[i][0], acc[i][1], acc[i][2], acc[i][3]);
            *reinterpret_cast<float4*>(&C[(size_t)gm * N + bn + tx * 4]) = v;
        }
    }
}

// ---------------- per-node attention coefficients ----------------
template<int F>
__global__ __launch_bounds__(256)
void alpha_kernel(const float* __restrict__ h, const float* __restrict__ a_src,
                  const float* __restrict__ a_dst, float* __restrict__ as_out,
                  float* __restrict__ ad_out) {
    int gt = blockIdx.x * blockDim.x + threadIdx.x;
    int node = gt >> 6;
    int lane = gt & 63;
    if (node >= N_NODES) return;
    const float* row = h + (size_t)node * F;
    float s = 0.f, d = 0.f;
    #pragma unroll
    for (int j = 0; j < F / 64; ++j) {
        float v = row[lane + 64 * j];
        s += v * a_src[lane + 64 * j];
        d += v * a_dst[lane + 64 * j];
    }
    #pragma unroll
    for (int off = 32; off; off >>= 1) {
        s += __shfl_down(s, off);
        d += __shfl_down(d, off);
    }
    if (lane == 0) { as_out[node] = s; ad_out[node] = d; }
}

// ---------------- fused segment softmax + aggregate (one wave / node) ----------------
template<int F, int RELU>
__global__ __launch_bounds__(256)
void aggregate_kernel(const float* __restrict__ h, const float* __restrict__ as_in,
                      const float* __restrict__ ad_in, const int* __restrict__ row_ptr,
                      const int* __restrict__ esrc, const float* __restrict__ bias,
                      float* __restrict__ out) {
    int gt = blockIdx.x * blockDim.x + threadIdx.x;
    int node = gt >> 6;
    int lane = gt & 63;
    if (node >= N_NODES) return;
    int beg = row_ptr[node], end = row_ptr[node + 1];
    float adn = ad_in[node];

    // pass 1: running max of leakyrelu(as[src]+ad[dst])
    float m = -INFINITY;
    for (int i = beg + lane; i < end; i += 64) {
        float e = as_in[esrc[i]] + adn;
        e = e > 0.f ? e : NEG_SLOPE * e;
        m = fmaxf(m, e);
    }
    #pragma unroll
    for (int off = 32; off; off >>= 1) m = fmaxf(m, __shfl_xor(m, off));

    // pass 2: denominator
    float z = 0.f;
    for (int i = beg + lane; i < end; i += 64) {
        float e = as_in[esrc[i]] + adn;
        e = e > 0.f ? e : NEG_SLOPE * e;
        z += __expf(e - m);
    }
    #pragma unroll
    for (int off = 32; off; off >>= 1) z += __shfl_xor(z, off);
    float inv_z = 1.f / z;

    // pass 3: weighted aggregate, vectorized: each lane owns F/64 contiguous floats
    constexpr int V = F / 64;   // 4 (F=256) or 2 (F=128)
    float acc[V] = {};
    for (int i = beg; i < end; ++i) {
        int s = esrc[i];
        float e = as_in[s] + adn;
        e = e > 0.f ? e : NEG_SLOPE * e;
        float w = __expf(e - m) * inv_z;
        const float* hr = h + (size_t)s * F + lane * V;
        #pragma unroll
        for (int j = 0; j < V; ++j) acc[j] += w * hr[j];
    }
    float* orow = out + (size_t)node * F + lane * V;
    const float* brow = bias + lane * V;
    #pragma unroll
    for (int j = 0; j < V; ++j) {
        float v = acc[j] + brow[j];
        if (RELU) v = fmaxf(v, 0.f);
        orow[j] = v;
    }
}

// ---------------- launch ----------------
extern "C" void kernel_launch(void* const* d_in, const int* in_sizes, int n_in,
                              void* d_out, int out_size, void* d_ws, size_t ws_size,
                              hipStream_t stream) {
    const float* x      = (const float*)d_in[0];
    const int*   ei     = (const int*)d_in[1];     // [2, 800000]
    const float* W1     = (const float*)d_in[2];
    const float* a1s    = (const float*)d_in[3];
    const float* a1d    = (const float*)d_in[4];
    const float* b1     = (const float*)d_in[5];
    const float* W2     = (const float*)d_in[6];
    const float* a2s    = (const float*)d_in[7];
    const float* a2d    = (const float*)d_in[8];
    const float* b2     = (const float*)d_in[9];
    float* out = (float*)d_out;

    const int* e_src = ei;
    const int* e_dst = ei + N_EDGESX;

    char* ws = (char*)d_ws;
    // offsets (256B aligned)
    const size_t OFF_H1   = 0;                              // N*256*4 = 51,200,000 (h1; later reused as h2)
    const size_t OFF_G1   = 51200000;                       // N*256*4
    const size_t OFF_AS   = 102400000;                      // N*4
    const size_t OFF_AD   = OFF_AS + 200192;
    const size_t OFF_RP   = OFF_AD + 200192;                // (N+1)*4
    const size_t OFF_CUR  = OFF_RP + 200448;                // N*4 (counts, then cursor)
    const size_t OFF_ESRC = OFF_CUR + 200192;               // E_TOT*4

    float* h1   = (float*)(ws + OFF_H1);
    float* g1   = (float*)(ws + OFF_G1);
    float* h2   = (float*)(ws + OFF_H1);   // alias: h1 dead after aggregate1
    float* as_b = (float*)(ws + OFF_AS);
    float* ad_b = (float*)(ws + OFF_AD);
    int* row_ptr = (int*)(ws + OFF_RP);
    int* cursor  = (int*)(ws + OFF_CUR);
    int* esrc    = (int*)(ws + OFF_ESRC);

    // --- CSR build ---
    hipMemsetAsync(cursor, 0, N_NODES * sizeof(int), stream);
    int egrid = (E_TOT + 255) / 256;
    count_kernel<<<egrid, 256, 0, stream>>>(e_dst, cursor);
    scan_kernel<<<1, 1024, 0, stream>>>(cursor, row_ptr);
    scatter_kernel<<<egrid, 256, 0, stream>>>(e_src, e_dst, cursor, esrc);

    int ngrid = (N_NODES * 64 + 255) / 256;   // one wave per node

    // --- layer 1 ---
    gemm64<<<dim3(HID_C / 64, (N_NODES + 63) / 64), 256, 0, stream>>>(x, W1, h1, N_NODES, HID_C, IN_C);
    alpha_kernel<HID_C><<<ngrid, 256, 0, stream>>>(h1, a1s, a1d, as_b, ad_b);
    aggregate_kernel<HID_C, 1><<<ngrid, 256, 0, stream>>>(h1, as_b, ad_b, row_ptr, esrc, b1, g1);

    // --- layer 2 ---
    gemm64<<<dim3(OUT_C / 64, (N_NODES + 63) / 64), 256, 0, stream>>>(g1, W2, h2, N_NODES, OUT_C, HID_C);
    alpha_kernel<OUT_C><<<ngrid, 256, 0, stream>>>(h2, a2s, a2d, as_b, ad_b);
    aggregate_kernel<OUT_C, 0><<<ngrid, 256, 0, stream>>>(h2, as_b, ad_b, row_ptr, esrc, b2, out);
}

// Round 2
// 476.081 us; speedup vs baseline: 1.3057x; 1.3057x over previous
//
#include <hip/hip_runtime.h>
#include <hip/hip_bf16.h>
#include <math.h>

#define N_NODES 50000
#define N_EDGESX 800000
#define E_TOT   (N_EDGESX + N_NODES)
#define IN_C 128
#define HID_C 256
#define OUT_C 128
#define NEG_SLOPE 0.2f

typedef __attribute__((ext_vector_type(8))) short short8;
typedef __attribute__((ext_vector_type(4))) short short4v;
typedef __attribute__((ext_vector_type(4))) float floatx4;
typedef __attribute__((ext_vector_type(2))) float floatx2;

// bf16 <-> f32 via bit ops (bf16 stored as raw short)
__device__ __forceinline__ float bf2f(short s) {
    unsigned u = ((unsigned)(unsigned short)s) << 16;
    float f; __builtin_memcpy(&f, &u, 4); return f;
}
__device__ __forceinline__ short f2bf(float f) {   // RNE
    unsigned u; __builtin_memcpy(&u, &f, 4);
    unsigned r = (u + 0x7FFFu + ((u >> 16) & 1u)) >> 16;
    return (short)r;
}

// ---------------- CSR build ----------------
__global__ void count_kernel(const int* __restrict__ dst, int* __restrict__ cnt) {
    int i = blockIdx.x * blockDim.x + threadIdx.x;
    if (i < E_TOT) {
        int d = (i < N_EDGESX) ? dst[i] : (i - N_EDGESX);
        atomicAdd(&cnt[d], 1);
    }
}

#define NBLK ((N_NODES + 1023) / 1024)   // 49

__global__ __launch_bounds__(1024)
void scan_a_kernel(const int* __restrict__ cnt, int* __restrict__ row_ptr, int* __restrict__ bsum) {
    __shared__ int buf[1024];
    int tid = threadIdx.x;
    int idx = blockIdx.x * 1024 + tid;
    int v = (idx < N_NODES) ? cnt[idx] : 0;
    buf[tid] = v;
    __syncthreads();
    for (int off = 1; off < 1024; off <<= 1) {
        int t = (tid >= off) ? buf[tid - off] : 0;
        __syncthreads();
        buf[tid] += t;
        __syncthreads();
    }
    if (idx < N_NODES) row_ptr[idx] = buf[tid] - v;   // local exclusive
    if (tid == 1023) bsum[blockIdx.x] = buf[1023];
}

__global__ void scan_b_kernel(int* __restrict__ bsum, int* __restrict__ row_ptr) {
    int lane = threadIdx.x;   // 64
    int v = (lane < NBLK) ? bsum[lane] : 0;
    int s = v;
    #pragma unroll
    for (int off = 1; off < 64; off <<= 1) {
        int t = __shfl_up(s, off);
        if (lane >= off) s += t;
    }
    if (lane < NBLK) bsum[lane] = s - v;   // exclusive block offsets
    if (lane == 63) row_ptr[N_NODES] = s;  // grand total
}

__global__ __launch_bounds__(1024)
void scan_c_kernel(int* __restrict__ row_ptr, const int* __restrict__ bsum, int* __restrict__ cursor) {
    int idx = blockIdx.x * 1024 + threadIdx.x;
    if (idx < N_NODES) {
        int v = row_ptr[idx] + bsum[blockIdx.x];
        row_ptr[idx] = v;
        cursor[idx] = v;
    }
}

__global__ void scatter_kernel(const int* __restrict__ src, const int* __restrict__ dst,
                               int* __restrict__ cursor, int* __restrict__ esrc) {
    int i = blockIdx.x * blockDim.x + threadIdx.x;
    if (i < E_TOT) {
        int s, d;
        if (i < N_EDGESX) { s = src[i]; d = dst[i]; }
        else { s = i - N_EDGESX; d = s; }
        int pos = atomicAdd(&cursor[d], 1);
        esrc[pos] = s;
    }
}

// ---------------- fp32 -> bf16 hi/lo split ----------------
__global__ void split_x_kernel(const float* __restrict__ in, short* __restrict__ hi,
                               short* __restrict__ lo, int n4) {
    int i = blockIdx.x * blockDim.x + threadIdx.x;
    if (i >= n4) return;
    floatx4 v = *(const floatx4*)&in[i * 4];
    short4v h, l;
    #pragma unroll
    for (int j = 0; j < 4; ++j) {
        float f = v[j];
        short hb = f2bf(f);
        h[j] = hb;
        l[j] = f2bf(f - bf2f(hb));
    }
    *(short4v*)&hi[i * 4] = h;
    *(short4v*)&lo[i * 4] = l;
}

// W[K][N] -> Wt hi/lo [N][K]
__global__ void splitT_kernel(const float* __restrict__ W, short* __restrict__ th,
                              short* __restrict__ tl, int K, int N) {
    int i = blockIdx.x * blockDim.x + threadIdx.x;
    if (i >= K * N) return;
    int k = i / N, n = i - k * N;
    float f = W[i];
    short hb = f2bf(f);
    th[n * K + k] = hb;
    tl[n * K + k] = f2bf(f - bf2f(hb));
}

// ---------------- split-bf16 MFMA GEMM ----------------
// C[M,N] = (Ah+Al)[M,K] @ (Bh+Bl)[K,N], Bt stored [N][K]. BM=128, BN=64, 4 waves.
template<int K, int OUTBF>
__global__ __launch_bounds__(256)
void gemm_mfma(const short* __restrict__ Ah, const short* __restrict__ Al,
               const short* __restrict__ Bth, const short* __restrict__ Btl,
               int N, float* __restrict__ Cf, short* __restrict__ Cb) {
    __shared__ short Ah_s[128][40];   // pitch 40 bf16 = 80B: 2-way-free banks
    __shared__ short Al_s[128][40];
    __shared__ short Bh_s[64][40];
    __shared__ short Bl_s[64][40];
    int tid = threadIdx.x;
    int lane = tid & 63, wave = tid >> 6;
    int wr = wave >> 1, wc = wave & 1;
    int bm = blockIdx.y * 128, bn = blockIdx.x * 64;
    int l15 = lane & 15, kf = (lane >> 4) * 8;

    floatx4 acc[4][2];
    #pragma unroll
    for (int i = 0; i < 4; ++i)
        #pragma unroll
        for (int j = 0; j < 2; ++j) acc[i][j] = (floatx4){0.f, 0.f, 0.f, 0.f};

    int arow = tid >> 1, ac0 = (tid & 1) * 16;
    int brow = tid >> 2, bc0 = (tid & 3) * 8;
    int agm = bm + arow;
    bool aval = agm < N_NODES;

    for (int k0 = 0; k0 < K; k0 += 32) {
        short8 va0 = {0,0,0,0,0,0,0,0}, va1 = va0, vl0 = va0, vl1 = va0;
        if (aval) {
            const short* pa = Ah + (size_t)agm * K + k0 + ac0;
            va0 = *(const short8*)pa; va1 = *(const short8*)(pa + 8);
            const short* pl = Al + (size_t)agm * K + k0 + ac0;
            vl0 = *(const short8*)pl; vl1 = *(const short8*)(pl + 8);
        }
        *(short8*)&Ah_s[arow][ac0]     = va0;
        *(short8*)&Ah_s[arow][ac0 + 8] = va1;
        *(short8*)&Al_s[arow][ac0]     = vl0;
        *(short8*)&Al_s[arow][ac0 + 8] = vl1;
        {
            const short* pb = Bth + (size_t)(bn + brow) * K + k0 + bc0;
            *(short8*)&Bh_s[brow][bc0] = *(const short8*)pb;
            const short* pb2 = Btl + (size_t)(bn + brow) * K + k0 + bc0;
            *(short8*)&Bl_s[brow][bc0] = *(const short8*)pb2;
        }
        __syncthreads();
        short8 afh[4], afl[4], bfh[2], bfl[2];
        #pragma unroll
        for (int mr = 0; mr < 4; ++mr) {
            int r = wr * 64 + mr * 16 + l15;
            afh[mr] = *(const short8*)&Ah_s[r][kf];
            afl[mr] = *(const short8*)&Al_s[r][kf];
        }
        #pragma unroll
        for (int nr = 0; nr < 2; ++nr) {
            int c = wc * 32 + nr * 16 + l15;
            bfh[nr] = *(const short8*)&Bh_s[c][kf];
            bfl[nr] = *(const short8*)&Bl_s[c][kf];
        }
        #pragma unroll
        for (int mr = 0; mr < 4; ++mr)
            #pragma unroll
            for (int nr = 0; nr < 2; ++nr) {
                acc[mr][nr] = __builtin_amdgcn_mfma_f32_16x16x32_bf16(afh[mr], bfh[nr], acc[mr][nr], 0, 0, 0);
                acc[mr][nr] = __builtin_amdgcn_mfma_f32_16x16x32_bf16(afh[mr], bfl[nr], acc[mr][nr], 0, 0, 0);
                acc[mr][nr] = __builtin_amdgcn_mfma_f32_16x16x32_bf16(afl[mr], bfh[nr], acc[mr][nr], 0, 0, 0);
            }
        __syncthreads();
    }
    #pragma unroll
    for (int mr = 0; mr < 4; ++mr) {
        #pragma unroll
        for (int reg = 0; reg < 4; ++reg) {
            int gr = bm + wr * 64 + mr * 16 + (lane >> 4) * 4 + reg;
            if (gr < N_NODES) {
                #pragma unroll
                for (int nr = 0; nr < 2; ++nr) {
                    int gc = bn + wc * 32 + nr * 16 + l15;
                    float v = acc[mr][nr][reg];
                    if (OUTBF) Cb[(size_t)gr * N + gc] = f2bf(v);
                    else       Cf[(size_t)gr * N + gc] = v;
                }
            }
        }
    }
}

// ---------------- per-node attention logits ----------------
__global__ __launch_bounds__(256)
void alpha_bf16_kernel(const short* __restrict__ h, const float* __restrict__ a_src,
                       const float* __restrict__ a_dst, float* __restrict__ as_out,
                       float* __restrict__ ad_out) {
    int gt = blockIdx.x * blockDim.x + threadIdx.x;
    int node = gt >> 6, lane = gt & 63;
    if (node >= N_NODES) return;
    short4v hv = *(const short4v*)&h[(size_t)node * HID_C + lane * 4];
    floatx4 as4 = *(const floatx4*)&a_src[lane * 4];
    floatx4 ad4 = *(const floatx4*)&a_dst[lane * 4];
    float s = 0.f, d = 0.f;
    #pragma unroll
    for (int j = 0; j < 4; ++j) {
        float v = bf2f(hv[j]);
        s += v * as4[j];
        d += v * ad4[j];
    }
    #pragma unroll
    for (int off = 32; off; off >>= 1) {
        s += __shfl_down(s, off);
        d += __shfl_down(d, off);
    }
    if (lane == 0) { as_out[node] = s; ad_out[node] = d; }
}

__global__ __launch_bounds__(256)
void alpha_f32_kernel(const float* __restrict__ h, const float* __restrict__ a_src,
                      const float* __restrict__ a_dst, float* __restrict__ as_out,
                      float* __restrict__ ad_out) {
    int gt = blockIdx.x * blockDim.x + threadIdx.x;
    int node = gt >> 6, lane = gt & 63;
    if (node >= N_NODES) return;
    floatx2 hv = *(const floatx2*)&h[(size_t)node * OUT_C + lane * 2];
    floatx2 as2 = *(const floatx2*)&a_src[lane * 2];
    floatx2 ad2 = *(const floatx2*)&a_dst[lane * 2];
    float s = hv[0] * as2[0] + hv[1] * as2[1];
    float d = hv[0] * ad2[0] + hv[1] * ad2[1];
    #pragma unroll
    for (int off = 32; off; off >>= 1) {
        s += __shfl_down(s, off);
        d += __shfl_down(d, off);
    }
    if (lane == 0) { as_out[node] = s; ad_out[node] = d; }
}

// ---------------- fused segment softmax + aggregate ----------------
// layer 1: bf16 h gather, relu, write g1 as hi/lo bf16 split
__global__ __launch_bounds__(256)
void aggregate_bf16_kernel(const short* __restrict__ h, const float* __restrict__ as_in,
                           const float* __restrict__ ad_in, const int* __restrict__ row_ptr,
                           const int* __restrict__ esrc, const float* __restrict__ bias,
                           short* __restrict__ g_hi, short* __restrict__ g_lo) {
    int gt = blockIdx.x * blockDim.x + threadIdx.x;
    int node = gt >> 6, lane = gt & 63;
    if (node >= N_NODES) return;
    int beg = row_ptr[node], end = row_ptr[node + 1];
    float adn = ad_in[node];

    float m = -INFINITY;
    for (int i = beg + lane; i < end; i += 64) {
        float e = as_in[esrc[i]] + adn;
        e = e > 0.f ? e : NEG_SLOPE * e;
        m = fmaxf(m, e);
    }
    #pragma unroll
    for (int off = 32; off; off >>= 1) m = fmaxf(m, __shfl_xor(m, off));

    float z = 0.f;
    for (int i = beg + lane; i < end; i += 64) {
        float e = as_in[esrc[i]] + adn;
        e = e > 0.f ? e : NEG_SLOPE * e;
        z += __expf(e - m);
    }
    #pragma unroll
    for (int off = 32; off; off >>= 1) z += __shfl_xor(z, off);
    float inv_z = 1.f / z;

    float acc[4] = {0.f, 0.f, 0.f, 0.f};
    for (int i = beg; i < end; ++i) {
        int s = esrc[i];
        float e = as_in[s] + adn;
        e = e > 0.f ? e : NEG_SLOPE * e;
        float w = __expf(e - m) * inv_z;
        short4v hv = *(const short4v*)&h[(size_t)s * HID_C + lane * 4];
        #pragma unroll
        for (int j = 0; j < 4; ++j) acc[j] += w * bf2f(hv[j]);
    }
    floatx4 b4 = *(const floatx4*)&bias[lane * 4];
    short4v oh, ol;
    #pragma unroll
    for (int j = 0; j < 4; ++j) {
        float v = fmaxf(acc[j] + b4[j], 0.f);   // + bias, relu
        short hb = f2bf(v);
        oh[j] = hb;
        ol[j] = f2bf(v - bf2f(hb));
    }
    *(short4v*)&g_hi[(size_t)node * HID_C + lane * 4] = oh;
    *(short4v*)&g_lo[(size_t)node * HID_C + lane * 4] = ol;
}

// layer 2: fp32 gather, + bias, write final out
__global__ __launch_bounds__(256)
void aggregate_f32_kernel(const float* __restrict__ h, const float* __restrict__ as_in,
                          const float* __restrict__ ad_in, const int* __restrict__ row_ptr,
                          const int* __restrict__ esrc, const float* __restrict__ bias,
                          float* __restrict__ out) {
    int gt = blockIdx.x * blockDim.x + threadIdx.x;
    int node = gt >> 6, lane = gt & 63;
    if (node >= N_NODES) return;
    int beg = row_ptr[node], end = row_ptr[node + 1];
    float adn = ad_in[node];

    float m = -INFINITY;
    for (int i = beg + lane; i < end; i += 64) {
        float e = as_in[esrc[i]] + adn;
        e = e > 0.f ? e : NEG_SLOPE * e;
        m = fmaxf(m, e);
    }
    #pragma unroll
    for (int off = 32; off; off >>= 1) m = fmaxf(m, __shfl_xor(m, off));

    float z = 0.f;
    for (int i = beg + lane; i < end; i += 64) {
        float e = as_in[esrc[i]] + adn;
        e = e > 0.f ? e : NEG_SLOPE * e;
        z += __expf(e - m);
    }
    #pragma unroll
    for (int off = 32; off; off >>= 1) z += __shfl_xor(z, off);
    float inv_z = 1.f / z;

    float a0 = 0.f, a1 = 0.f;
    for (int i = beg; i < end; ++i) {
        int s = esrc[i];
        float e = as_in[s] + adn;
        e = e > 0.f ? e : NEG_SLOPE * e;
        float w = __expf(e - m) * inv_z;
        floatx2 hv = *(const floatx2*)&h[(size_t)s * OUT_C + lane * 2];
        a0 += w * hv[0];
        a1 += w * hv[1];
    }
    floatx2 b2 = *(const floatx2*)&bias[lane * 2];
    floatx2 o; o[0] = a0 + b2[0]; o[1] = a1 + b2[1];
    *(floatx2*)&out[(size_t)node * OUT_C + lane * 2] = o;
}

// ---------------- launch ----------------
extern "C" void kernel_launch(void* const* d_in, const int* in_sizes, int n_in,
                              void* d_out, int out_size, void* d_ws, size_t ws_size,
                              hipStream_t stream) {
    const float* x   = (const float*)d_in[0];
    const int*   ei  = (const int*)d_in[1];
    const float* W1  = (const float*)d_in[2];
    const float* a1s = (const float*)d_in[3];
    const float* a1d = (const float*)d_in[4];
    const float* b1  = (const float*)d_in[5];
    const float* W2  = (const float*)d_in[6];
    const float* a2s = (const float*)d_in[7];
    const float* a2d = (const float*)d_in[8];
    const float* b2  = (const float*)d_in[9];
    float* out = (float*)d_out;

    const int* e_src = ei;
    const int* e_dst = ei + N_EDGESX;

    char* ws = (char*)d_ws;
    const size_t OFF_XHI  = 0;              // 12,800,000
    const size_t OFF_XLO  = 12800000;
    const size_t OFF_H1   = 25600000;       // bf16 [N][256]
    const size_t OFF_G1HI = 51200000;
    const size_t OFF_G1LO = 76800000;
    const size_t OFF_H2   = 102400000;      // fp32 [N][128]
    const size_t OFF_W1TH = 128000000;
    const size_t OFF_W1TL = 128065536;
    const size_t OFF_W2TH = 128131072;
    const size_t OFF_W2TL = 128196608;
    const size_t OFF_AS   = 128262144;
    const size_t OFF_AD   = 128462336;
    const size_t OFF_RP   = 128662528;
    const size_t OFF_CNT  = 128862976;
    const size_t OFF_CUR  = 129063168;
    const size_t OFF_BSUM = 129263360;
    const size_t OFF_ESRC = 129263616;

    short* xh   = (short*)(ws + OFF_XHI);
    short* xl   = (short*)(ws + OFF_XLO);
    short* h1   = (short*)(ws + OFF_H1);
    short* g1h  = (short*)(ws + OFF_G1HI);
    short* g1l  = (short*)(ws + OFF_G1LO);
    float* h2   = (float*)(ws + OFF_H2);
    short* w1th = (short*)(ws + OFF_W1TH);
    short* w1tl = (short*)(ws + OFF_W1TL);
    short* w2th = (short*)(ws + OFF_W2TH);
    short* w2tl = (short*)(ws + OFF_W2TL);
    float* as_b = (float*)(ws + OFF_AS);
    float* ad_b = (float*)(ws + OFF_AD);
    int* row_ptr = (int*)(ws + OFF_RP);
    int* cnt     = (int*)(ws + OFF_CNT);
    int* cursor  = (int*)(ws + OFF_CUR);
    int* bsum    = (int*)(ws + OFF_BSUM);
    int* esrc    = (int*)(ws + OFF_ESRC);

    // --- CSR build ---
    hipMemsetAsync(cnt, 0, N_NODES * sizeof(int), stream);
    int egrid = (E_TOT + 255) / 256;
    count_kernel<<<egrid, 256, 0, stream>>>(e_dst, cnt);
    scan_a_kernel<<<NBLK, 1024, 0, stream>>>(cnt, row_ptr, bsum);
    scan_b_kernel<<<1, 64, 0, stream>>>(bsum, row_ptr);
    scan_c_kernel<<<NBLK, 1024, 0, stream>>>(row_ptr, bsum, cursor);
    scatter_kernel<<<egrid, 256, 0, stream>>>(e_src, e_dst, cursor, esrc);

    // --- input splits ---
    split_x_kernel<<<(N_NODES * IN_C / 4 + 255) / 256, 256, 0, stream>>>(x, xh, xl, N_NODES * IN_C / 4);
    splitT_kernel<<<(IN_C * HID_C + 255) / 256, 256, 0, stream>>>(W1, w1th, w1tl, IN_C, HID_C);
    splitT_kernel<<<(HID_C * OUT_C + 255) / 256, 256, 0, stream>>>(W2, w2th, w2tl, HID_C, OUT_C);

    int ngrid = (N_NODES * 64 + 255) / 256;

    // --- layer 1 ---
    gemm_mfma<IN_C, 1><<<dim3(HID_C / 64, (N_NODES + 127) / 128), 256, 0, stream>>>(
        xh, xl, w1th, w1tl, HID_C, nullptr, h1);
    alpha_bf16_kernel<<<ngrid, 256, 0, stream>>>(h1, a1s, a1d, as_b, ad_b);
    aggregate_bf16_kernel<<<ngrid, 256, 0, stream>>>(h1, as_b, ad_b, row_ptr, esrc, b1, g1h, g1l);

    // --- layer 2 ---
    gemm_mfma<HID_C, 0><<<dim3(OUT_C / 64, (N_NODES + 127) / 128), 256, 0, stream>>>(
        g1h, g1l, w2th, w2tl, OUT_C, h2, nullptr);
    alpha_f32_kernel<<<ngrid, 256, 0, stream>>>(h2, a2s, a2d, as_b, ad_b);
    aggregate_f32_kernel<<<ngrid, 256, 0, stream>>>(h2, as_b, ad_b, row_ptr, esrc, b2, out);
}

// Round 3
// 402.373 us; speedup vs baseline: 1.5449x; 1.1832x over previous
//
#include <hip/hip_runtime.h>
#include <hip/hip_bf16.h>
#include <math.h>

#define N_NODES 50000
#define N_EDGESX 800000
#define E_TOT   (N_EDGESX + N_NODES)
#define IN_C 128
#define HID_C 256
#define OUT_C 128
#define NEG_SLOPE 0.2f

typedef __attribute__((ext_vector_type(8))) short short8;
typedef __attribute__((ext_vector_type(4))) short short4v;
typedef __attribute__((ext_vector_type(4))) float floatx4;
typedef __attribute__((ext_vector_type(2))) float floatx2;

__device__ __forceinline__ float bf2f(short s) {
    unsigned u = ((unsigned)(unsigned short)s) << 16;
    float f; __builtin_memcpy(&f, &u, 4); return f;
}
__device__ __forceinline__ short f2bf(float f) {   // RNE
    unsigned u; __builtin_memcpy(&u, &f, 4);
    unsigned r = (u + 0x7FFFu + ((u >> 16) & 1u)) >> 16;
    return (short)r;
}

// ---------------- CSR build ----------------
__global__ void count_kernel(const int* __restrict__ dst, int* __restrict__ cnt) {
    int i = blockIdx.x * blockDim.x + threadIdx.x;
    if (i < E_TOT) {
        int d = (i < N_EDGESX) ? dst[i] : (i - N_EDGESX);
        atomicAdd(&cnt[d], 1);
    }
}

#define NBLK ((N_NODES + 1023) / 1024)   // 49

__global__ __launch_bounds__(1024)
void scan_a_kernel(const int* __restrict__ cnt, int* __restrict__ row_ptr, int* __restrict__ bsum) {
    __shared__ int buf[1024];
    int tid = threadIdx.x;
    int idx = blockIdx.x * 1024 + tid;
    int v = (idx < N_NODES) ? cnt[idx] : 0;
    buf[tid] = v;
    __syncthreads();
    for (int off = 1; off < 1024; off <<= 1) {
        int t = (tid >= off) ? buf[tid - off] : 0;
        __syncthreads();
        buf[tid] += t;
        __syncthreads();
    }
    if (idx < N_NODES) row_ptr[idx] = buf[tid] - v;
    if (tid == 1023) bsum[blockIdx.x] = buf[1023];
}

__global__ void scan_b_kernel(int* __restrict__ bsum, int* __restrict__ row_ptr) {
    int lane = threadIdx.x;   // 64
    int v = (lane < NBLK) ? bsum[lane] : 0;
    int s = v;
    #pragma unroll
    for (int off = 1; off < 64; off <<= 1) {
        int t = __shfl_up(s, off);
        if (lane >= off) s += t;
    }
    if (lane < NBLK) bsum[lane] = s - v;
    if (lane == 63) row_ptr[N_NODES] = s;
}

__global__ __launch_bounds__(1024)
void scan_c_kernel(int* __restrict__ row_ptr, const int* __restrict__ bsum, int* __restrict__ cursor) {
    int idx = blockIdx.x * 1024 + threadIdx.x;
    if (idx < N_NODES) {
        int v = row_ptr[idx] + bsum[blockIdx.x];
        row_ptr[idx] = v;
        cursor[idx] = v;
    }
}

__global__ void scatter_kernel(const int* __restrict__ src, const int* __restrict__ dst,
                               int* __restrict__ cursor, int* __restrict__ esrc,
                               int* __restrict__ edst) {
    int i = blockIdx.x * blockDim.x + threadIdx.x;
    if (i < E_TOT) {
        int s, d;
        if (i < N_EDGESX) { s = src[i]; d = dst[i]; }
        else { s = i - N_EDGESX; d = s; }
        int pos = atomicAdd(&cursor[d], 1);
        esrc[pos] = s;
        edst[pos] = d;
    }
}

// ---------------- per-edge logits (coalesced) ----------------
__global__ void ew_kernel(const int* __restrict__ esrc, const int* __restrict__ edst,
                          const float* __restrict__ as_in, const float* __restrict__ ad_in,
                          float* __restrict__ ew) {
    int i = blockIdx.x * blockDim.x + threadIdx.x;
    if (i >= E_TOT) return;
    float e = as_in[esrc[i]] + ad_in[edst[i]];
    ew[i] = e > 0.f ? e : NEG_SLOPE * e;
}

// ---------------- W[K][N] -> Wt hi/lo [N][K] ----------------
__global__ void splitT_kernel(const float* __restrict__ W, short* __restrict__ th,
                              short* __restrict__ tl, int K, int N) {
    int i = blockIdx.x * blockDim.x + threadIdx.x;
    if (i >= K * N) return;
    int k = i / N, n = i - k * N;
    float f = W[i];
    short hb = f2bf(f);
    th[n * K + k] = hb;
    tl[n * K + k] = f2bf(f - bf2f(hb));
}

// ---------------- split-bf16 MFMA GEMM ----------------
// C[M,N] = (Ah+Al)[M,K] @ (Bh+Bl)[K,N], Bt stored [N][K]. BM=128, BN=64, 4 waves.
// AF32: A is fp32, split to hi/lo in-register during staging.
template<int K, int AF32, int OUTBF>
__global__ __launch_bounds__(256)
void gemm_mfma(const void* __restrict__ Ap, const short* __restrict__ Alo,
               const short* __restrict__ Bth, const short* __restrict__ Btl,
               int N, float* __restrict__ Cf, short* __restrict__ Cb) {
    __shared__ short Ah_s[128][40];
    __shared__ short Al_s[128][40];
    __shared__ short Bh_s[64][40];
    __shared__ short Bl_s[64][40];
    int tid = threadIdx.x;
    int lane = tid & 63, wave = tid >> 6;
    int wr = wave >> 1, wc = wave & 1;
    int bm = blockIdx.y * 128, bn = blockIdx.x * 64;
    int l15 = lane & 15, kf = (lane >> 4) * 8;

    floatx4 acc[4][2];
    #pragma unroll
    for (int i = 0; i < 4; ++i)
        #pragma unroll
        for (int j = 0; j < 2; ++j) acc[i][j] = (floatx4){0.f, 0.f, 0.f, 0.f};

    int arow = tid >> 1, ac0 = (tid & 1) * 16;
    int brow = tid >> 2, bc0 = (tid & 3) * 8;
    int agm = bm + arow;
    bool aval = agm < N_NODES;

    for (int k0 = 0; k0 < K; k0 += 32) {
        if (AF32) {
            float f[16];
            #pragma unroll
            for (int j = 0; j < 16; ++j) f[j] = 0.f;
            if (aval) {
                const float* pa = (const float*)Ap + (size_t)agm * K + k0 + ac0;
                #pragma unroll
                for (int q = 0; q < 4; ++q) {
                    floatx4 v = *(const floatx4*)(pa + q * 4);
                    #pragma unroll
                    for (int j = 0; j < 4; ++j) f[q * 4 + j] = v[j];
                }
            }
            short8 hh0, hh1, ll0, ll1;
            #pragma unroll
            for (int j = 0; j < 8; ++j) {
                short hb = f2bf(f[j]);
                hh0[j] = hb; ll0[j] = f2bf(f[j] - bf2f(hb));
                short hb1 = f2bf(f[j + 8]);
                hh1[j] = hb1; ll1[j] = f2bf(f[j + 8] - bf2f(hb1));
            }
            *(short8*)&Ah_s[arow][ac0]     = hh0;
            *(short8*)&Ah_s[arow][ac0 + 8] = hh1;
            *(short8*)&Al_s[arow][ac0]     = ll0;
            *(short8*)&Al_s[arow][ac0 + 8] = ll1;
        } else {
            short8 va0 = {0,0,0,0,0,0,0,0}, va1 = va0, vl0 = va0, vl1 = va0;
            if (aval) {
                const short* pa = (const short*)Ap + (size_t)agm * K + k0 + ac0;
                va0 = *(const short8*)pa; va1 = *(const short8*)(pa + 8);
                const short* pl = Alo + (size_t)agm * K + k0 + ac0;
                vl0 = *(const short8*)pl; vl1 = *(const short8*)(pl + 8);
            }
            *(short8*)&Ah_s[arow][ac0]     = va0;
            *(short8*)&Ah_s[arow][ac0 + 8] = va1;
            *(short8*)&Al_s[arow][ac0]     = vl0;
            *(short8*)&Al_s[arow][ac0 + 8] = vl1;
        }
        {
            const short* pb = Bth + (size_t)(bn + brow) * K + k0 + bc0;
            *(short8*)&Bh_s[brow][bc0] = *(const short8*)pb;
            const short* pb2 = Btl + (size_t)(bn + brow) * K + k0 + bc0;
            *(short8*)&Bl_s[brow][bc0] = *(const short8*)pb2;
        }
        __syncthreads();
        short8 afh[4], afl[4], bfh[2], bfl[2];
        #pragma unroll
        for (int mr = 0; mr < 4; ++mr) {
            int r = wr * 64 + mr * 16 + l15;
            afh[mr] = *(const short8*)&Ah_s[r][kf];
            afl[mr] = *(const short8*)&Al_s[r][kf];
        }
        #pragma unroll
        for (int nr = 0; nr < 2; ++nr) {
            int c = wc * 32 + nr * 16 + l15;
            bfh[nr] = *(const short8*)&Bh_s[c][kf];
            bfl[nr] = *(const short8*)&Bl_s[c][kf];
        }
        #pragma unroll
        for (int mr = 0; mr < 4; ++mr)
            #pragma unroll
            for (int nr = 0; nr < 2; ++nr) {
                acc[mr][nr] = __builtin_amdgcn_mfma_f32_16x16x32_bf16(afh[mr], bfh[nr], acc[mr][nr], 0, 0, 0);
                acc[mr][nr] = __builtin_amdgcn_mfma_f32_16x16x32_bf16(afh[mr], bfl[nr], acc[mr][nr], 0, 0, 0);
                acc[mr][nr] = __builtin_amdgcn_mfma_f32_16x16x32_bf16(afl[mr], bfh[nr], acc[mr][nr], 0, 0, 0);
            }
        __syncthreads();
    }
    #pragma unroll
    for (int mr = 0; mr < 4; ++mr) {
        #pragma unroll
        for (int reg = 0; reg < 4; ++reg) {
            int gr = bm + wr * 64 + mr * 16 + (lane >> 4) * 4 + reg;
            if (gr < N_NODES) {
                #pragma unroll
                for (int nr = 0; nr < 2; ++nr) {
                    int gc = bn + wc * 32 + nr * 16 + l15;
                    float v = acc[mr][nr][reg];
                    if (OUTBF) Cb[(size_t)gr * N + gc] = f2bf(v);
                    else       Cf[(size_t)gr * N + gc] = v;
                }
            }
        }
    }
}

// ---------------- per-node attention logits ----------------
__global__ __launch_bounds__(256)
void alpha_bf16_kernel(const short* __restrict__ h, const float* __restrict__ a_src,
                       const float* __restrict__ a_dst, float* __restrict__ as_out,
                       float* __restrict__ ad_out) {
    int gt = blockIdx.x * blockDim.x + threadIdx.x;
    int node = gt >> 6, lane = gt & 63;
    if (node >= N_NODES) return;
    short4v hv = *(const short4v*)&h[(size_t)node * HID_C + lane * 4];
    floatx4 as4 = *(const floatx4*)&a_src[lane * 4];
    floatx4 ad4 = *(const floatx4*)&a_dst[lane * 4];
    float s = 0.f, d = 0.f;
    #pragma unroll
    for (int j = 0; j < 4; ++j) {
        float v = bf2f(hv[j]);
        s += v * as4[j];
        d += v * ad4[j];
    }
    #pragma unroll
    for (int off = 32; off; off >>= 1) {
        s += __shfl_down(s, off);
        d += __shfl_down(d, off);
    }
    if (lane == 0) { as_out[node] = s; ad_out[node] = d; }
}

__global__ __launch_bounds__(256)
void alpha_f32_kernel(const float* __restrict__ h, const float* __restrict__ a_src,
                      const float* __restrict__ a_dst, float* __restrict__ as_out,
                      float* __restrict__ ad_out) {
    int gt = blockIdx.x * blockDim.x + threadIdx.x;
    int node = gt >> 6, lane = gt & 63;
    if (node >= N_NODES) return;
    floatx2 hv = *(const floatx2*)&h[(size_t)node * OUT_C + lane * 2];
    floatx2 as2 = *(const floatx2*)&a_src[lane * 2];
    floatx2 ad2 = *(const floatx2*)&a_dst[lane * 2];
    float s = hv[0] * as2[0] + hv[1] * as2[1];
    float d = hv[0] * ad2[0] + hv[1] * ad2[1];
    #pragma unroll
    for (int off = 32; off; off >>= 1) {
        s += __shfl_down(s, off);
        d += __shfl_down(d, off);
    }
    if (lane == 0) { as_out[node] = s; ad_out[node] = d; }
}

// ---------------- fused segment softmax + aggregate ----------------
// layer 1: bf16 h gather (2 edges/wave, 16B/lane), relu, write g1 hi/lo
__global__ __launch_bounds__(256)
void aggregate_bf16_kernel(const short* __restrict__ h, const float* __restrict__ ew,
                           const int* __restrict__ row_ptr, const int* __restrict__ esrc,
                           const float* __restrict__ bias,
                           short* __restrict__ g_hi, short* __restrict__ g_lo) {
    int gt = blockIdx.x * blockDim.x + threadIdx.x;
    int node = gt >> 6, lane = gt & 63;
    if (node >= N_NODES) return;
    int beg = row_ptr[node], end = row_ptr[node + 1];

    float m = -INFINITY;
    for (int i = beg + lane; i < end; i += 64) m = fmaxf(m, ew[i]);
    #pragma unroll
    for (int off = 32; off; off >>= 1) m = fmaxf(m, __shfl_xor(m, off));

    float z = 0.f;
    for (int i = beg + lane; i < end; i += 64) z += __expf(ew[i] - m);
    #pragma unroll
    for (int off = 32; off; off >>= 1) z += __shfl_xor(z, off);
    float inv_z = 1.f / z;

    int half = lane >> 5, l = lane & 31;
    float acc[8] = {};
    #pragma unroll 2
    for (int i = beg; i < end; i += 2) {
        int e = i + half;
        bool v = e < end;
        int s = esrc[v ? e : i];
        float w = v ? __expf(ew[e] - m) * inv_z : 0.f;
        short8 hv = *(const short8*)&h[(size_t)s * HID_C + l * 8];
        #pragma unroll
        for (int j = 0; j < 8; ++j) acc[j] += w * bf2f(hv[j]);
    }
    #pragma unroll
    for (int j = 0; j < 8; ++j) acc[j] += __shfl_xor(acc[j], 32);

    if (lane < 32) {
        floatx4 b0 = *(const floatx4*)&bias[l * 8];
        floatx4 b1 = *(const floatx4*)&bias[l * 8 + 4];
        short8 oh, ol;
        #pragma unroll
        for (int j = 0; j < 8; ++j) {
            float bv = (j < 4) ? b0[j] : b1[j - 4];
            float vv = fmaxf(acc[j] + bv, 0.f);
            short hb = f2bf(vv);
            oh[j] = hb;
            ol[j] = f2bf(vv - bf2f(hb));
        }
        *(short8*)&g_hi[(size_t)node * HID_C + l * 8] = oh;
        *(short8*)&g_lo[(size_t)node * HID_C + l * 8] = ol;
    }
}

// layer 2: fp32 gather (2 edges/wave, 16B/lane), + bias, final out
__global__ __launch_bounds__(256)
void aggregate_f32_kernel(const float* __restrict__ h, const float* __restrict__ ew,
                          const int* __restrict__ row_ptr, const int* __restrict__ esrc,
                          const float* __restrict__ bias, float* __restrict__ out) {
    int gt = blockIdx.x * blockDim.x + threadIdx.x;
    int node = gt >> 6, lane = gt & 63;
    if (node >= N_NODES) return;
    int beg = row_ptr[node], end = row_ptr[node + 1];

    float m = -INFINITY;
    for (int i = beg + lane; i < end; i += 64) m = fmaxf(m, ew[i]);
    #pragma unroll
    for (int off = 32; off; off >>= 1) m = fmaxf(m, __shfl_xor(m, off));

    float z = 0.f;
    for (int i = beg + lane; i < end; i += 64) z += __expf(ew[i] - m);
    #pragma unroll
    for (int off = 32; off; off >>= 1) z += __shfl_xor(z, off);
    float inv_z = 1.f / z;

    int half = lane >> 5, l = lane & 31;
    float a0 = 0.f, a1 = 0.f, a2 = 0.f, a3 = 0.f;
    #pragma unroll 2
    for (int i = beg; i < end; i += 2) {
        int e = i + half;
        bool v = e < end;
        int s = esrc[v ? e : i];
        float w = v ? __expf(ew[e] - m) * inv_z : 0.f;
        floatx4 hv = *(const floatx4*)&h[(size_t)s * OUT_C + l * 4];
        a0 += w * hv[0]; a1 += w * hv[1]; a2 += w * hv[2]; a3 += w * hv[3];
    }
    a0 += __shfl_xor(a0, 32); a1 += __shfl_xor(a1, 32);
    a2 += __shfl_xor(a2, 32); a3 += __shfl_xor(a3, 32);

    if (lane < 32) {
        floatx4 b4 = *(const floatx4*)&bias[l * 4];
        floatx4 o;
        o[0] = a0 + b4[0]; o[1] = a1 + b4[1]; o[2] = a2 + b4[2]; o[3] = a3 + b4[3];
        *(floatx4*)&out[(size_t)node * OUT_C + l * 4] = o;
    }
}

// ---------------- launch ----------------
extern "C" void kernel_launch(void* const* d_in, const int* in_sizes, int n_in,
                              void* d_out, int out_size, void* d_ws, size_t ws_size,
                              hipStream_t stream) {
    const float* x   = (const float*)d_in[0];
    const int*   ei  = (const int*)d_in[1];
    const float* W1  = (const float*)d_in[2];
    const float* a1s = (const float*)d_in[3];
    const float* a1d = (const float*)d_in[4];
    const float* b1  = (const float*)d_in[5];
    const float* W2  = (const float*)d_in[6];
    const float* a2s = (const float*)d_in[7];
    const float* a2d = (const float*)d_in[8];
    const float* b2  = (const float*)d_in[9];
    float* out = (float*)d_out;

    const int* e_src = ei;
    const int* e_dst = ei + N_EDGESX;

    char* ws = (char*)d_ws;
    const size_t OFF_H1   = 0;            // bf16 [N][256] = 25.6MB
    const size_t OFF_G1HI = 25600000;
    const size_t OFF_G1LO = 51200000;
    const size_t OFF_H2   = 76800000;     // fp32 [N][128] = 25.6MB
    const size_t OFF_W1TH = 102400000;
    const size_t OFF_W1TL = 102465536;
    const size_t OFF_W2TH = 102531072;
    const size_t OFF_W2TL = 102596608;
    const size_t OFF_AS   = 102662144;
    const size_t OFF_AD   = 102862336;
    const size_t OFF_RP   = 103062528;
    const size_t OFF_CNT  = 103262976;
    const size_t OFF_CUR  = 103463168;
    const size_t OFF_BSUM = 103663360;
    const size_t OFF_ESRC = 103663616;    // E_TOT*4 = 3.4MB
    const size_t OFF_EDST = 107063616;
    const size_t OFF_EW   = 110463616;    // E_TOT*4 + pad

    short* h1   = (short*)(ws + OFF_H1);
    short* g1h  = (short*)(ws + OFF_G1HI);
    short* g1l  = (short*)(ws + OFF_G1LO);
    float* h2   = (float*)(ws + OFF_H2);
    short* w1th = (short*)(ws + OFF_W1TH);
    short* w1tl = (short*)(ws + OFF_W1TL);
    short* w2th = (short*)(ws + OFF_W2TH);
    short* w2tl = (short*)(ws + OFF_W2TL);
    float* as_b = (float*)(ws + OFF_AS);
    float* ad_b = (float*)(ws + OFF_AD);
    int* row_ptr = (int*)(ws + OFF_RP);
    int* cnt     = (int*)(ws + OFF_CNT);
    int* cursor  = (int*)(ws + OFF_CUR);
    int* bsum    = (int*)(ws + OFF_BSUM);
    int* esrc    = (int*)(ws + OFF_ESRC);
    int* edst    = (int*)(ws + OFF_EDST);
    float* ewb   = (float*)(ws + OFF_EW);

    // --- CSR build ---
    hipMemsetAsync(cnt, 0, N_NODES * sizeof(int), stream);
    int egrid = (E_TOT + 255) / 256;
    count_kernel<<<egrid, 256, 0, stream>>>(e_dst, cnt);
    scan_a_kernel<<<NBLK, 1024, 0, stream>>>(cnt, row_ptr, bsum);
    scan_b_kernel<<<1, 64, 0, stream>>>(bsum, row_ptr);
    scan_c_kernel<<<NBLK, 1024, 0, stream>>>(row_ptr, bsum, cursor);
    scatter_kernel<<<egrid, 256, 0, stream>>>(e_src, e_dst, cursor, esrc, edst);

    // --- weight splits ---
    splitT_kernel<<<(IN_C * HID_C + 255) / 256, 256, 0, stream>>>(W1, w1th, w1tl, IN_C, HID_C);
    splitT_kernel<<<(HID_C * OUT_C + 255) / 256, 256, 0, stream>>>(W2, w2th, w2tl, HID_C, OUT_C);

    int ngrid = (N_NODES * 64 + 255) / 256;

    // --- layer 1 ---
    gemm_mfma<IN_C, 1, 1><<<dim3(HID_C / 64, (N_NODES + 127) / 128), 256, 0, stream>>>(
        x, nullptr, w1th, w1tl, HID_C, nullptr, h1);
    alpha_bf16_kernel<<<ngrid, 256, 0, stream>>>(h1, a1s, a1d, as_b, ad_b);
    ew_kernel<<<egrid, 256, 0, stream>>>(esrc, edst, as_b, ad_b, ewb);
    aggregate_bf16_kernel<<<ngrid, 256, 0, stream>>>(h1, ewb, row_ptr, esrc, b1, g1h, g1l);

    // --- layer 2 ---
    gemm_mfma<HID_C, 0, 0><<<dim3(OUT_C / 64, (N_NODES + 127) / 128), 256, 0, stream>>>(
        g1h, g1l, w2th, w2tl, OUT_C, h2, nullptr);
    alpha_f32_kernel<<<ngrid, 256, 0, stream>>>(h2, a2s, a2d, as_b, ad_b);
    ew_kernel<<<egrid, 256, 0, stream>>>(esrc, edst, as_b, ad_b, ewb);
    aggregate_f32_kernel<<<ngrid, 256, 0, stream>>>(h2, ewb, row_ptr, esrc, b2, out);
}

// Round 4
// 379.950 us; speedup vs baseline: 1.6361x; 1.0590x over previous
//
#include <hip/hip_runtime.h>
#include <hip/hip_bf16.h>
#include <math.h>

#define N_NODES 50000
#define N_EDGESX 800000
#define E_TOT   (N_EDGESX + N_NODES)
#define IN_C 128
#define HID_C 256
#define OUT_C 128
#define NEG_SLOPE 0.2f

typedef __attribute__((ext_vector_type(8))) short short8;
typedef __attribute__((ext_vector_type(4))) short short4v;
typedef __attribute__((ext_vector_type(4))) float floatx4;
typedef __attribute__((ext_vector_type(2))) float floatx2;

__device__ __forceinline__ float bf2f(short s) {
    unsigned u = ((unsigned)(unsigned short)s) << 16;
    float f; __builtin_memcpy(&f, &u, 4); return f;
}
__device__ __forceinline__ short f2bf(float f) {   // RNE
    unsigned u; __builtin_memcpy(&u, &f, 4);
    unsigned r = (u + 0x7FFFu + ((u >> 16) & 1u)) >> 16;
    return (short)r;
}

// ---------------- CSR build ----------------
__global__ void count_kernel(const int* __restrict__ dst, int* __restrict__ cnt) {
    int i = blockIdx.x * blockDim.x + threadIdx.x;
    if (i < E_TOT) {
        int d = (i < N_EDGESX) ? dst[i] : (i - N_EDGESX);
        atomicAdd(&cnt[d], 1);
    }
}

#define NBLK ((N_NODES + 1023) / 1024)   // 49

__global__ __launch_bounds__(1024)
void scan_a_kernel(const int* __restrict__ cnt, int* __restrict__ row_ptr, int* __restrict__ bsum) {
    __shared__ int buf[1024];
    int tid = threadIdx.x;
    int idx = blockIdx.x * 1024 + tid;
    int v = (idx < N_NODES) ? cnt[idx] : 0;
    buf[tid] = v;
    __syncthreads();
    for (int off = 1; off < 1024; off <<= 1) {
        int t = (tid >= off) ? buf[tid - off] : 0;
        __syncthreads();
        buf[tid] += t;
        __syncthreads();
    }
    if (idx < N_NODES) row_ptr[idx] = buf[tid] - v;
    if (tid == 1023) bsum[blockIdx.x] = buf[1023];
}

__global__ void scan_b_kernel(int* __restrict__ bsum, int* __restrict__ row_ptr) {
    int lane = threadIdx.x;   // 64
    int v = (lane < NBLK) ? bsum[lane] : 0;
    int s = v;
    #pragma unroll
    for (int off = 1; off < 64; off <<= 1) {
        int t = __shfl_up(s, off);
        if (lane >= off) s += t;
    }
    if (lane < NBLK) bsum[lane] = s - v;
    if (lane == 63) row_ptr[N_NODES] = s;
}

__global__ __launch_bounds__(1024)
void scan_c_kernel(int* __restrict__ row_ptr, const int* __restrict__ bsum, int* __restrict__ cursor) {
    int idx = blockIdx.x * 1024 + threadIdx.x;
    if (idx < N_NODES) {
        int v = row_ptr[idx] + bsum[blockIdx.x];
        row_ptr[idx] = v;
        cursor[idx] = v;
    }
}

__global__ void scatter_kernel(const int* __restrict__ src, const int* __restrict__ dst,
                               int* __restrict__ cursor, int* __restrict__ esrc,
                               int* __restrict__ edst) {
    int i = blockIdx.x * blockDim.x + threadIdx.x;
    if (i < E_TOT) {
        int s, d;
        if (i < N_EDGESX) { s = src[i]; d = dst[i]; }
        else { s = i - N_EDGESX; d = s; }
        int pos = atomicAdd(&cursor[d], 1);
        esrc[pos] = s;
        edst[pos] = d;
    }
}

// ---------------- per-edge logits (coalesced) ----------------
__global__ void ew_kernel(const int* __restrict__ esrc, const int* __restrict__ edst,
                          const float* __restrict__ as_in, const float* __restrict__ ad_in,
                          float* __restrict__ ew) {
    int i = blockIdx.x * blockDim.x + threadIdx.x;
    if (i >= E_TOT) return;
    float e = as_in[esrc[i]] + ad_in[edst[i]];
    ew[i] = e > 0.f ? e : NEG_SLOPE * e;
}

// ---------------- W[K][N] -> Wt hi/lo [N][K] ----------------
__global__ void splitT_kernel(const float* __restrict__ W, short* __restrict__ th,
                              short* __restrict__ tl, int K, int N) {
    int i = blockIdx.x * blockDim.x + threadIdx.x;
    if (i >= K * N) return;
    int k = i / N, n = i - k * N;
    float f = W[i];
    short hb = f2bf(f);
    th[n * K + k] = hb;
    tl[n * K + k] = f2bf(f - bf2f(hb));
}

// ---------------- split-bf16 MFMA GEMM ----------------
// C[M,N] = (Ah+Al)[M,K] @ (Bh+Bl)[K,N], Bt stored [N][K]. BM=128, BN=64, 4 waves.
template<int K, int AF32, int OUTBF>
__global__ __launch_bounds__(256)
void gemm_mfma(const void* __restrict__ Ap, const short* __restrict__ Alo,
               const short* __restrict__ Bth, const short* __restrict__ Btl,
               int N, float* __restrict__ Cf, short* __restrict__ Cb) {
    __shared__ short Ah_s[128][40];
    __shared__ short Al_s[128][40];
    __shared__ short Bh_s[64][40];
    __shared__ short Bl_s[64][40];
    int tid = threadIdx.x;
    int lane = tid & 63, wave = tid >> 6;
    int wr = wave >> 1, wc = wave & 1;
    int bm = blockIdx.y * 128, bn = blockIdx.x * 64;
    int l15 = lane & 15, kf = (lane >> 4) * 8;

    floatx4 acc[4][2];
    #pragma unroll
    for (int i = 0; i < 4; ++i)
        #pragma unroll
        for (int j = 0; j < 2; ++j) acc[i][j] = (floatx4){0.f, 0.f, 0.f, 0.f};

    int arow = tid >> 1, ac0 = (tid & 1) * 16;
    int brow = tid >> 2, bc0 = (tid & 3) * 8;
    int agm = bm + arow;
    bool aval = agm < N_NODES;

    for (int k0 = 0; k0 < K; k0 += 32) {
        if (AF32) {
            float f[16];
            #pragma unroll
            for (int j = 0; j < 16; ++j) f[j] = 0.f;
            if (aval) {
                const float* pa = (const float*)Ap + (size_t)agm * K + k0 + ac0;
                #pragma unroll
                for (int q = 0; q < 4; ++q) {
                    floatx4 v = *(const floatx4*)(pa + q * 4);
                    #pragma unroll
                    for (int j = 0; j < 4; ++j) f[q * 4 + j] = v[j];
                }
            }
            short8 hh0, hh1, ll0, ll1;
            #pragma unroll
            for (int j = 0; j < 8; ++j) {
                short hb = f2bf(f[j]);
                hh0[j] = hb; ll0[j] = f2bf(f[j] - bf2f(hb));
                short hb1 = f2bf(f[j + 8]);
                hh1[j] = hb1; ll1[j] = f2bf(f[j + 8] - bf2f(hb1));
            }
            *(short8*)&Ah_s[arow][ac0]     = hh0;
            *(short8*)&Ah_s[arow][ac0 + 8] = hh1;
            *(short8*)&Al_s[arow][ac0]     = ll0;
            *(short8*)&Al_s[arow][ac0 + 8] = ll1;
        } else {
            short8 va0 = {0,0,0,0,0,0,0,0}, va1 = va0, vl0 = va0, vl1 = va0;
            if (aval) {
                const short* pa = (const short*)Ap + (size_t)agm * K + k0 + ac0;
                va0 = *(const short8*)pa; va1 = *(const short8*)(pa + 8);
                const short* pl = Alo + (size_t)agm * K + k0 + ac0;
                vl0 = *(const short8*)pl; vl1 = *(const short8*)(pl + 8);
            }
            *(short8*)&Ah_s[arow][ac0]     = va0;
            *(short8*)&Ah_s[arow][ac0 + 8] = va1;
            *(short8*)&Al_s[arow][ac0]     = vl0;
            *(short8*)&Al_s[arow][ac0 + 8] = vl1;
        }
        {
            const short* pb = Bth + (size_t)(bn + brow) * K + k0 + bc0;
            *(short8*)&Bh_s[brow][bc0] = *(const short8*)pb;
            const short* pb2 = Btl + (size_t)(bn + brow) * K + k0 + bc0;
            *(short8*)&Bl_s[brow][bc0] = *(const short8*)pb2;
        }
        __syncthreads();
        short8 afh[4], afl[4], bfh[2], bfl[2];
        #pragma unroll
        for (int mr = 0; mr < 4; ++mr) {
            int r = wr * 64 + mr * 16 + l15;
            afh[mr] = *(const short8*)&Ah_s[r][kf];
            afl[mr] = *(const short8*)&Al_s[r][kf];
        }
        #pragma unroll
        for (int nr = 0; nr < 2; ++nr) {
            int c = wc * 32 + nr * 16 + l15;
            bfh[nr] = *(const short8*)&Bh_s[c][kf];
            bfl[nr] = *(const short8*)&Bl_s[c][kf];
        }
        #pragma unroll
        for (int mr = 0; mr < 4; ++mr)
            #pragma unroll
            for (int nr = 0; nr < 2; ++nr) {
                acc[mr][nr] = __builtin_amdgcn_mfma_f32_16x16x32_bf16(afh[mr], bfh[nr], acc[mr][nr], 0, 0, 0);
                acc[mr][nr] = __builtin_amdgcn_mfma_f32_16x16x32_bf16(afh[mr], bfl[nr], acc[mr][nr], 0, 0, 0);
                acc[mr][nr] = __builtin_amdgcn_mfma_f32_16x16x32_bf16(afl[mr], bfh[nr], acc[mr][nr], 0, 0, 0);
            }
        __syncthreads();
    }
    #pragma unroll
    for (int mr = 0; mr < 4; ++mr) {
        #pragma unroll
        for (int reg = 0; reg < 4; ++reg) {
            int gr = bm + wr * 64 + mr * 16 + (lane >> 4) * 4 + reg;
            if (gr < N_NODES) {
                #pragma unroll
                for (int nr = 0; nr < 2; ++nr) {
                    int gc = bn + wc * 32 + nr * 16 + l15;
                    float v = acc[mr][nr][reg];
                    if (OUTBF) Cb[(size_t)gr * N + gc] = f2bf(v);
                    else       Cf[(size_t)gr * N + gc] = v;
                }
            }
        }
    }
}

// ---------------- per-node attention logits (bf16 h) ----------------
__global__ __launch_bounds__(256)
void alpha_bf16_256(const short* __restrict__ h, const float* __restrict__ a_src,
                    const float* __restrict__ a_dst, float* __restrict__ as_out,
                    float* __restrict__ ad_out) {
    int gt = blockIdx.x * blockDim.x + threadIdx.x;
    int node = gt >> 6, lane = gt & 63;
    if (node >= N_NODES) return;
    short4v hv = *(const short4v*)&h[(size_t)node * HID_C + lane * 4];
    floatx4 as4 = *(const floatx4*)&a_src[lane * 4];
    floatx4 ad4 = *(const floatx4*)&a_dst[lane * 4];
    float s = 0.f, d = 0.f;
    #pragma unroll
    for (int j = 0; j < 4; ++j) {
        float v = bf2f(hv[j]);
        s += v * as4[j];
        d += v * ad4[j];
    }
    #pragma unroll
    for (int off = 32; off; off >>= 1) {
        s += __shfl_down(s, off);
        d += __shfl_down(d, off);
    }
    if (lane == 0) { as_out[node] = s; ad_out[node] = d; }
}

__global__ __launch_bounds__(256)
void alpha_bf16_128(const short* __restrict__ h, const float* __restrict__ a_src,
                    const float* __restrict__ a_dst, float* __restrict__ as_out,
                    float* __restrict__ ad_out) {
    int gt = blockIdx.x * blockDim.x + threadIdx.x;
    int node = gt >> 6, lane = gt & 63;
    if (node >= N_NODES) return;
    unsigned u = *(const unsigned*)&h[(size_t)node * OUT_C + lane * 2];
    float v0 = bf2f((short)(u & 0xFFFFu));
    float v1 = bf2f((short)(u >> 16));
    floatx2 as2 = *(const floatx2*)&a_src[lane * 2];
    floatx2 ad2 = *(const floatx2*)&a_dst[lane * 2];
    float s = v0 * as2[0] + v1 * as2[1];
    float d = v0 * ad2[0] + v1 * ad2[1];
    #pragma unroll
    for (int off = 32; off; off >>= 1) {
        s += __shfl_down(s, off);
        d += __shfl_down(d, off);
    }
    if (lane == 0) { as_out[node] = s; ad_out[node] = d; }
}

// ---------------- fused segment softmax + aggregate ----------------
// One wave per node. Online (max,sum) in one pass, then 4 edges in flight
// (4 groups of 16 lanes; each group loads one full row per edge).

// layer 1: F=256 bf16 in, g1 hi/lo bf16 out, +bias +relu
__global__ __launch_bounds__(256)
void aggregate1_kernel(const short* __restrict__ h, const float* __restrict__ ew,
                       const int* __restrict__ row_ptr, const int* __restrict__ esrc,
                       const float* __restrict__ bias,
                       short* __restrict__ g_hi, short* __restrict__ g_lo) {
    int gt = blockIdx.x * blockDim.x + threadIdx.x;
    int node = gt >> 6, lane = gt & 63;
    if (node >= N_NODES) return;
    int beg = row_ptr[node], end = row_ptr[node + 1];

    float ml = -1e30f, zl = 0.f;
    for (int i = beg + lane; i < end; i += 64) {
        float e = ew[i];
        float mn = fmaxf(ml, e);
        zl = zl * __expf(ml - mn) + __expf(e - mn);
        ml = mn;
    }
    #pragma unroll
    for (int off = 32; off; off >>= 1) {
        float mo = __shfl_xor(ml, off);
        float zo = __shfl_xor(zl, off);
        float mn = fmaxf(ml, mo);
        zl = zl * __expf(ml - mn) + zo * __expf(mo - mn);
        ml = mn;
    }
    float m = ml;
    float inv_z = 1.f / zl;

    int grp = lane >> 4, l = lane & 15;
    float acc[16] = {};
    for (int i = beg; i < end; i += 4) {
        int e = i + grp;
        bool v = e < end;
        int s = esrc[v ? e : beg];
        float w = v ? __expf(ew[e] - m) * inv_z : 0.f;
        const short* hr = &h[(size_t)s * HID_C + l * 16];
        short8 h0 = *(const short8*)hr;
        short8 h1 = *(const short8*)(hr + 8);
        #pragma unroll
        for (int j = 0; j < 8; ++j) {
            acc[j]     += w * bf2f(h0[j]);
            acc[j + 8] += w * bf2f(h1[j]);
        }
    }
    #pragma unroll
    for (int j = 0; j < 16; ++j) {
        acc[j] += __shfl_xor(acc[j], 16);
        acc[j] += __shfl_xor(acc[j], 32);
    }

    if (lane < 16) {
        const float* brow = &bias[l * 16];
        short8 oh0, oh1, ol0, ol1;
        #pragma unroll
        for (int j = 0; j < 8; ++j) {
            float v0 = fmaxf(acc[j] + brow[j], 0.f);
            short hb0 = f2bf(v0);
            oh0[j] = hb0; ol0[j] = f2bf(v0 - bf2f(hb0));
            float v1 = fmaxf(acc[j + 8] + brow[j + 8], 0.f);
            short hb1 = f2bf(v1);
            oh1[j] = hb1; ol1[j] = f2bf(v1 - bf2f(hb1));
        }
        short* gh = &g_hi[(size_t)node * HID_C + l * 16];
        short* gl = &g_lo[(size_t)node * HID_C + l * 16];
        *(short8*)gh = oh0; *(short8*)(gh + 8) = oh1;
        *(short8*)gl = ol0; *(short8*)(gl + 8) = ol1;
    }
}

// layer 2: F=128 bf16 in, fp32 out, +bias
__global__ __launch_bounds__(256)
void aggregate2_kernel(const short* __restrict__ h, const float* __restrict__ ew,
                       const int* __restrict__ row_ptr, const int* __restrict__ esrc,
                       const float* __restrict__ bias, float* __restrict__ out) {
    int gt = blockIdx.x * blockDim.x + threadIdx.x;
    int node = gt >> 6, lane = gt & 63;
    if (node >= N_NODES) return;
    int beg = row_ptr[node], end = row_ptr[node + 1];

    float ml = -1e30f, zl = 0.f;
    for (int i = beg + lane; i < end; i += 64) {
        float e = ew[i];
        float mn = fmaxf(ml, e);
        zl = zl * __expf(ml - mn) + __expf(e - mn);
        ml = mn;
    }
    #pragma unroll
    for (int off = 32; off; off >>= 1) {
        float mo = __shfl_xor(ml, off);
        float zo = __shfl_xor(zl, off);
        float mn = fmaxf(ml, mo);
        zl = zl * __expf(ml - mn) + zo * __expf(mo - mn);
        ml = mn;
    }
    float m = ml;
    float inv_z = 1.f / zl;

    int grp = lane >> 4, l = lane & 15;
    float acc[8] = {};
    for (int i = beg; i < end; i += 4) {
        int e = i + grp;
        bool v = e < end;
        int s = esrc[v ? e : beg];
        float w = v ? __expf(ew[e] - m) * inv_z : 0.f;
        short8 hv = *(const short8*)&h[(size_t)s * OUT_C + l * 8];
        #pragma unroll
        for (int j = 0; j < 8; ++j) acc[j] += w * bf2f(hv[j]);
    }
    #pragma unroll
    for (int j = 0; j < 8; ++j) {
        acc[j] += __shfl_xor(acc[j], 16);
        acc[j] += __shfl_xor(acc[j], 32);
    }

    if (lane < 16) {
        const float* brow = &bias[l * 8];
        floatx4 o0, o1;
        #pragma unroll
        for (int j = 0; j < 4; ++j) {
            o0[j] = acc[j] + brow[j];
            o1[j] = acc[j + 4] + brow[j + 4];
        }
        float* orow = &out[(size_t)node * OUT_C + l * 8];
        *(floatx4*)orow = o0;
        *(floatx4*)(orow + 4) = o1;
    }
}

// ---------------- launch ----------------
extern "C" void kernel_launch(void* const* d_in, const int* in_sizes, int n_in,
                              void* d_out, int out_size, void* d_ws, size_t ws_size,
                              hipStream_t stream) {
    const float* x   = (const float*)d_in[0];
    const int*   ei  = (const int*)d_in[1];
    const float* W1  = (const float*)d_in[2];
    const float* a1s = (const float*)d_in[3];
    const float* a1d = (const float*)d_in[4];
    const float* b1  = (const float*)d_in[5];
    const float* W2  = (const float*)d_in[6];
    const float* a2s = (const float*)d_in[7];
    const float* a2d = (const float*)d_in[8];
    const float* b2  = (const float*)d_in[9];
    float* out = (float*)d_out;

    const int* e_src = ei;
    const int* e_dst = ei + N_EDGESX;

    char* ws = (char*)d_ws;
    const size_t OFF_H1   = 0;            // bf16 [N][256] = 25.6MB
    const size_t OFF_G1HI = 25600000;
    const size_t OFF_G1LO = 51200000;
    const size_t OFF_H2   = 76800000;     // bf16 [N][128] = 12.8MB
    const size_t OFF_W1TH = 89600000;
    const size_t OFF_W1TL = 89665536;
    const size_t OFF_W2TH = 89731072;
    const size_t OFF_W2TL = 89796608;
    const size_t OFF_AS   = 89862144;
    const size_t OFF_AD   = 90062336;
    const size_t OFF_RP   = 90262528;
    const size_t OFF_CNT  = 90462976;
    const size_t OFF_CUR  = 90663168;
    const size_t OFF_BSUM = 90863360;
    const size_t OFF_ESRC = 90863616;     // E_TOT*4 = 3.4MB
    const size_t OFF_EDST = 94263616;
    const size_t OFF_EW   = 97663616;

    short* h1   = (short*)(ws + OFF_H1);
    short* g1h  = (short*)(ws + OFF_G1HI);
    short* g1l  = (short*)(ws + OFF_G1LO);
    short* h2   = (short*)(ws + OFF_H2);
    short* w1th = (short*)(ws + OFF_W1TH);
    short* w1tl = (short*)(ws + OFF_W1TL);
    short* w2th = (short*)(ws + OFF_W2TH);
    short* w2tl = (short*)(ws + OFF_W2TL);
    float* as_b = (float*)(ws + OFF_AS);
    float* ad_b = (float*)(ws + OFF_AD);
    int* row_ptr = (int*)(ws + OFF_RP);
    int* cnt     = (int*)(ws + OFF_CNT);
    int* cursor  = (int*)(ws + OFF_CUR);
    int* bsum    = (int*)(ws + OFF_BSUM);
    int* esrc    = (int*)(ws + OFF_ESRC);
    int* edst    = (int*)(ws + OFF_EDST);
    float* ewb   = (float*)(ws + OFF_EW);

    // --- CSR build ---
    hipMemsetAsync(cnt, 0, N_NODES * sizeof(int), stream);
    int egrid = (E_TOT + 255) / 256;
    count_kernel<<<egrid, 256, 0, stream>>>(e_dst, cnt);
    scan_a_kernel<<<NBLK, 1024, 0, stream>>>(cnt, row_ptr, bsum);
    scan_b_kernel<<<1, 64, 0, stream>>>(bsum, row_ptr);
    scan_c_kernel<<<NBLK, 1024, 0, stream>>>(row_ptr, bsum, cursor);
    scatter_kernel<<<egrid, 256, 0, stream>>>(e_src, e_dst, cursor, esrc, edst);

    // --- weight splits ---
    splitT_kernel<<<(IN_C * HID_C + 255) / 256, 256, 0, stream>>>(W1, w1th, w1tl, IN_C, HID_C);
    splitT_kernel<<<(HID_C * OUT_C + 255) / 256, 256, 0, stream>>>(W2, w2th, w2tl, HID_C, OUT_C);

    int ngrid = (N_NODES * 64 + 255) / 256;

    // --- layer 1 ---
    gemm_mfma<IN_C, 1, 1><<<dim3(HID_C / 64, (N_NODES + 127) / 128), 256, 0, stream>>>(
        x, nullptr, w1th, w1tl, HID_C, nullptr, h1);
    alpha_bf16_256<<<ngrid, 256, 0, stream>>>(h1, a1s, a1d, as_b, ad_b);
    ew_kernel<<<egrid, 256, 0, stream>>>(esrc, edst, as_b, ad_b, ewb);
    aggregate1_kernel<<<ngrid, 256, 0, stream>>>(h1, ewb, row_ptr, esrc, b1, g1h, g1l);

    // --- layer 2 ---
    gemm_mfma<HID_C, 0, 1><<<dim3(OUT_C / 64, (N_NODES + 127) / 128), 256, 0, stream>>>(
        g1h, g1l, w2th, w2tl, OUT_C, nullptr, h2);
    alpha_bf16_128<<<ngrid, 256, 0, stream>>>(h2, a2s, a2d, as_b, ad_b);
    ew_kernel<<<egrid, 256, 0, stream>>>(esrc, edst, as_b, ad_b, ewb);
    aggregate2_kernel<<<ngrid, 256, 0, stream>>>(h2, ewb, row_ptr, esrc, b2, out);
}

// Round 5
// 366.576 us; speedup vs baseline: 1.6958x; 1.0365x over previous
//
#include <hip/hip_runtime.h>
#include <hip/hip_bf16.h>
#include <math.h>

#define N_NODES 50000
#define N_EDGESX 800000
#define E_TOT   (N_EDGESX + N_NODES)
#define IN_C 128
#define HID_C 256
#define OUT_C 128
#define NEG_SLOPE 0.2f

typedef __attribute__((ext_vector_type(8))) short short8;
typedef __attribute__((ext_vector_type(4))) float floatx4;
typedef __attribute__((ext_vector_type(2))) float floatx2;

__device__ __forceinline__ float bf2f(short s) {
    unsigned u = ((unsigned)(unsigned short)s) << 16;
    float f; __builtin_memcpy(&f, &u, 4); return f;
}
__device__ __forceinline__ short f2bf(float f) {   // RNE
    unsigned u; __builtin_memcpy(&u, &f, 4);
    unsigned r = (u + 0x7FFFu + ((u >> 16) & 1u)) >> 16;
    return (short)r;
}

// ---------------- projected attention vectors: p[k] = sum_n W[k][n]*a[n] ----------------
template<int KROWS, int NCOLS>
__global__ __launch_bounds__(256)
void gemv_p_kernel(const float* __restrict__ W, const float* __restrict__ a_s,
                   const float* __restrict__ a_d, float* __restrict__ ps, float* __restrict__ pd) {
    int t = threadIdx.x;
    int k = t & (KROWS - 1);
    const float* av = (t < KROWS) ? a_s : a_d;
    float* pv = (t < KROWS) ? ps : pd;
    const float* row = W + (size_t)k * NCOLS;
    float s = 0.f;
    for (int n = 0; n < NCOLS; ++n) s += row[n] * av[n];
    pv[k] = s;
}

// ---------------- alpha1 from x + x->bf16 split (fused, one x pass) ----------------
__global__ __launch_bounds__(256)
void alpha_x_kernel(const float* __restrict__ x, const float* __restrict__ ps,
                    const float* __restrict__ pd, float* __restrict__ as_out,
                    float* __restrict__ ad_out, short* __restrict__ xb) {
    int gt = blockIdx.x * blockDim.x + threadIdx.x;
    int node = gt >> 6, lane = gt & 63;
    if (node >= N_NODES) return;
    floatx2 xv = *(const floatx2*)&x[(size_t)node * IN_C + lane * 2];
    floatx2 s2 = *(const floatx2*)&ps[lane * 2];
    floatx2 d2 = *(const floatx2*)&pd[lane * 2];
    float s = xv[0] * s2[0] + xv[1] * s2[1];
    float d = xv[0] * d2[0] + xv[1] * d2[1];
    unsigned pack = (unsigned)(unsigned short)f2bf(xv[0]) | ((unsigned)(unsigned short)f2bf(xv[1]) << 16);
    *(unsigned*)&xb[(size_t)node * IN_C + lane * 2] = pack;
    #pragma unroll
    for (int off = 32; off; off >>= 1) {
        s += __shfl_down(s, off);
        d += __shfl_down(d, off);
    }
    if (lane == 0) { as_out[node] = s; ad_out[node] = d; }
}

// ---------------- CSR build ----------------
__global__ void count_kernel(const int* __restrict__ dst, int* __restrict__ cnt) {
    int i = blockIdx.x * blockDim.x + threadIdx.x;
    if (i < E_TOT) {
        int d = (i < N_EDGESX) ? dst[i] : (i - N_EDGESX);
        atomicAdd(&cnt[d], 1);
    }
}

#define NBLK ((N_NODES + 1023) / 1024)   // 49

__global__ __launch_bounds__(1024)
void scan_a_kernel(const int* __restrict__ cnt, int* __restrict__ row_ptr, int* __restrict__ bsum) {
    __shared__ int buf[1024];
    int tid = threadIdx.x;
    int idx = blockIdx.x * 1024 + tid;
    int v = (idx < N_NODES) ? cnt[idx] : 0;
    buf[tid] = v;
    __syncthreads();
    for (int off = 1; off < 1024; off <<= 1) {
        int t = (tid >= off) ? buf[tid - off] : 0;
        __syncthreads();
        buf[tid] += t;
        __syncthreads();
    }
    if (idx < N_NODES) row_ptr[idx] = buf[tid] - v;
    if (tid == 1023) bsum[blockIdx.x] = buf[1023];
}

__global__ void scan_b_kernel(int* __restrict__ bsum, int* __restrict__ row_ptr) {
    int lane = threadIdx.x;   // 64
    int v = (lane < NBLK) ? bsum[lane] : 0;
    int s = v;
    #pragma unroll
    for (int off = 1; off < 64; off <<= 1) {
        int t = __shfl_up(s, off);
        if (lane >= off) s += t;
    }
    if (lane < NBLK) bsum[lane] = s - v;
    if (lane == 63) row_ptr[N_NODES] = s;
}

__global__ __launch_bounds__(1024)
void scan_c_kernel(int* __restrict__ row_ptr, const int* __restrict__ bsum, int* __restrict__ cursor) {
    int idx = blockIdx.x * 1024 + threadIdx.x;
    if (idx < N_NODES) {
        int v = row_ptr[idx] + bsum[blockIdx.x];
        row_ptr[idx] = v;
        cursor[idx] = v;
    }
}

// scatter + fused layer-1 edge logits
__global__ void scatter_kernel(const int* __restrict__ src, const int* __restrict__ dst,
                               int* __restrict__ cursor, int* __restrict__ esrc,
                               int* __restrict__ edst, const float* __restrict__ as_in,
                               const float* __restrict__ ad_in, float* __restrict__ ew1) {
    int i = blockIdx.x * blockDim.x + threadIdx.x;
    if (i < E_TOT) {
        int s, d;
        if (i < N_EDGESX) { s = src[i]; d = dst[i]; }
        else { s = i - N_EDGESX; d = s; }
        int pos = atomicAdd(&cursor[d], 1);
        esrc[pos] = s;
        edst[pos] = d;
        float e = as_in[s] + ad_in[d];
        ew1[pos] = e > 0.f ? e : NEG_SLOPE * e;
    }
}

// ---------------- per-edge logits for layer 2 ----------------
__global__ void ew_kernel(const int* __restrict__ esrc, const int* __restrict__ edst,
                          const float* __restrict__ as_in, const float* __restrict__ ad_in,
                          float* __restrict__ ew) {
    int i = blockIdx.x * blockDim.x + threadIdx.x;
    if (i >= E_TOT) return;
    float e = as_in[esrc[i]] + ad_in[edst[i]];
    ew[i] = e > 0.f ? e : NEG_SLOPE * e;
}

// ---------------- W[K][N] -> Wt hi/lo [N][K] ----------------
__global__ void splitT_kernel(const float* __restrict__ W, short* __restrict__ th,
                              short* __restrict__ tl, int K, int N) {
    int i = blockIdx.x * blockDim.x + threadIdx.x;
    if (i >= K * N) return;
    int k = i / N, n = i - k * N;
    float f = W[i];
    short hb = f2bf(f);
    th[n * K + k] = hb;
    tl[n * K + k] = f2bf(f - bf2f(hb));
}

// ---------------- split-bf16 MFMA GEMM ----------------
// C = (Ah+Al)[M,K] @ (Bh+Bl)[K,N], Bt stored [N][K]. BM=128, BN=64, 4 waves.
// OUTMODE 1: plain bf16 -> C0.  OUTMODE 2: relu(v+bias[gc]) -> hi/lo C0/C1.
template<int K, int OUTMODE>
__global__ __launch_bounds__(256)
void gemm_mfma(const short* __restrict__ Ah, const short* __restrict__ Al,
               const short* __restrict__ Bth, const short* __restrict__ Btl,
               int N, const float* __restrict__ bias,
               short* __restrict__ C0, short* __restrict__ C1) {
    __shared__ short Ah_s[128][40];
    __shared__ short Al_s[128][40];
    __shared__ short Bh_s[64][40];
    __shared__ short Bl_s[64][40];
    int tid = threadIdx.x;
    int lane = tid & 63, wave = tid >> 6;
    int wr = wave >> 1, wc = wave & 1;
    int bm = blockIdx.y * 128, bn = blockIdx.x * 64;
    int l15 = lane & 15, kf = (lane >> 4) * 8;

    floatx4 acc[4][2];
    #pragma unroll
    for (int i = 0; i < 4; ++i)
        #pragma unroll
        for (int j = 0; j < 2; ++j) acc[i][j] = (floatx4){0.f, 0.f, 0.f, 0.f};

    int arow = tid >> 1, ac0 = (tid & 1) * 16;
    int brow = tid >> 2, bc0 = (tid & 3) * 8;
    int agm = bm + arow;
    bool aval = agm < N_NODES;

    for (int k0 = 0; k0 < K; k0 += 32) {
        short8 va0 = {0,0,0,0,0,0,0,0}, va1 = va0, vl0 = va0, vl1 = va0;
        if (aval) {
            const short* pa = Ah + (size_t)agm * K + k0 + ac0;
            va0 = *(const short8*)pa; va1 = *(const short8*)(pa + 8);
            const short* pl = Al + (size_t)agm * K + k0 + ac0;
            vl0 = *(const short8*)pl; vl1 = *(const short8*)(pl + 8);
        }
        *(short8*)&Ah_s[arow][ac0]     = va0;
        *(short8*)&Ah_s[arow][ac0 + 8] = va1;
        *(short8*)&Al_s[arow][ac0]     = vl0;
        *(short8*)&Al_s[arow][ac0 + 8] = vl1;
        {
            const short* pb = Bth + (size_t)(bn + brow) * K + k0 + bc0;
            *(short8*)&Bh_s[brow][bc0] = *(const short8*)pb;
            const short* pb2 = Btl + (size_t)(bn + brow) * K + k0 + bc0;
            *(short8*)&Bl_s[brow][bc0] = *(const short8*)pb2;
        }
        __syncthreads();
        short8 afh[4], afl[4], bfh[2], bfl[2];
        #pragma unroll
        for (int mr = 0; mr < 4; ++mr) {
            int r = wr * 64 + mr * 16 + l15;
            afh[mr] = *(const short8*)&Ah_s[r][kf];
            afl[mr] = *(const short8*)&Al_s[r][kf];
        }
        #pragma unroll
        for (int nr = 0; nr < 2; ++nr) {
            int c = wc * 32 + nr * 16 + l15;
            bfh[nr] = *(const short8*)&Bh_s[c][kf];
            bfl[nr] = *(const short8*)&Bl_s[c][kf];
        }
        #pragma unroll
        for (int mr = 0; mr < 4; ++mr)
            #pragma unroll
            for (int nr = 0; nr < 2; ++nr) {
                acc[mr][nr] = __builtin_amdgcn_mfma_f32_16x16x32_bf16(afh[mr], bfh[nr], acc[mr][nr], 0, 0, 0);
                acc[mr][nr] = __builtin_amdgcn_mfma_f32_16x16x32_bf16(afh[mr], bfl[nr], acc[mr][nr], 0, 0, 0);
                acc[mr][nr] = __builtin_amdgcn_mfma_f32_16x16x32_bf16(afl[mr], bfh[nr], acc[mr][nr], 0, 0, 0);
            }
        __syncthreads();
    }
    float bv[2];
    if (OUTMODE == 2) {
        #pragma unroll
        for (int nr = 0; nr < 2; ++nr) bv[nr] = bias[bn + wc * 32 + nr * 16 + l15];
    }
    #pragma unroll
    for (int mr = 0; mr < 4; ++mr) {
        #pragma unroll
        for (int reg = 0; reg < 4; ++reg) {
            int gr = bm + wr * 64 + mr * 16 + (lane >> 4) * 4 + reg;
            if (gr < N_NODES) {
                #pragma unroll
                for (int nr = 0; nr < 2; ++nr) {
                    int gc = bn + wc * 32 + nr * 16 + l15;
                    float v = acc[mr][nr][reg];
                    if (OUTMODE == 1) {
                        C0[(size_t)gr * N + gc] = f2bf(v);
                    } else {
                        v = fmaxf(v + bv[nr], 0.f);
                        short hb = f2bf(v);
                        C0[(size_t)gr * N + gc] = hb;
                        C1[(size_t)gr * N + gc] = f2bf(v - bf2f(hb));
                    }
                }
            }
        }
    }
}

// ---------------- alpha2 from h2 (bf16) ----------------
__global__ __launch_bounds__(256)
void alpha_bf16_128(const short* __restrict__ h, const float* __restrict__ a_src,
                    const float* __restrict__ a_dst, float* __restrict__ as_out,
                    float* __restrict__ ad_out) {
    int gt = blockIdx.x * blockDim.x + threadIdx.x;
    int node = gt >> 6, lane = gt & 63;
    if (node >= N_NODES) return;
    unsigned u = *(const unsigned*)&h[(size_t)node * OUT_C + lane * 2];
    float v0 = bf2f((short)(u & 0xFFFFu));
    float v1 = bf2f((short)(u >> 16));
    floatx2 as2 = *(const floatx2*)&a_src[lane * 2];
    floatx2 ad2 = *(const floatx2*)&a_dst[lane * 2];
    float s = v0 * as2[0] + v1 * as2[1];
    float d = v0 * ad2[0] + v1 * ad2[1];
    #pragma unroll
    for (int off = 32; off; off >>= 1) {
        s += __shfl_down(s, off);
        d += __shfl_down(d, off);
    }
    if (lane == 0) { as_out[node] = s; ad_out[node] = d; }
}

// ---------------- fused segment softmax + aggregate (F=128 bf16 rows) ----------------
// One wave/node: online (max,sum), then 4 edges in flight via 4x16-lane groups.
// OUT==0: u hi/lo bf16 (pre-GEMM1 aggregate of x). OUT==1: fp32 out + bias (final).
template<int OUT>
__global__ __launch_bounds__(256)
void aggregate_kernel(const short* __restrict__ h, const float* __restrict__ ew,
                      const int* __restrict__ row_ptr, const int* __restrict__ esrc,
                      const float* __restrict__ bias,
                      short* __restrict__ o_hi, short* __restrict__ o_lo,
                      float* __restrict__ o_f32) {
    int gt = blockIdx.x * blockDim.x + threadIdx.x;
    int node = gt >> 6, lane = gt & 63;
    if (node >= N_NODES) return;
    int beg = row_ptr[node], end = row_ptr[node + 1];

    float ml = -1e30f, zl = 0.f;
    for (int i = beg + lane; i < end; i += 64) {
        float e = ew[i];
        float mn = fmaxf(ml, e);
        zl = zl * __expf(ml - mn) + __expf(e - mn);
        ml = mn;
    }
    #pragma unroll
    for (int off = 32; off; off >>= 1) {
        float mo = __shfl_xor(ml, off);
        float zo = __shfl_xor(zl, off);
        float mn = fmaxf(ml, mo);
        zl = zl * __expf(ml - mn) + zo * __expf(mo - mn);
        ml = mn;
    }
    float m = ml;
    float inv_z = 1.f / zl;

    int grp = lane >> 4, l = lane & 15;
    float acc[8] = {};
    for (int i = beg; i < end; i += 4) {
        int e = i + grp;
        bool v = e < end;
        int s = esrc[v ? e : beg];
        float w = v ? __expf(ew[e] - m) * inv_z : 0.f;
        short8 hv = *(const short8*)&h[(size_t)s * 128 + l * 8];
        #pragma unroll
        for (int j = 0; j < 8; ++j) acc[j] += w * bf2f(hv[j]);
    }
    #pragma unroll
    for (int j = 0; j < 8; ++j) {
        acc[j] += __shfl_xor(acc[j], 16);
        acc[j] += __shfl_xor(acc[j], 32);
    }

    if (lane < 16) {
        if (OUT == 0) {
            short8 oh, ol;
            #pragma unroll
            for (int j = 0; j < 8; ++j) {
                short hb = f2bf(acc[j]);
                oh[j] = hb;
                ol[j] = f2bf(acc[j] - bf2f(hb));
            }
            *(short8*)&o_hi[(size_t)node * 128 + l * 8] = oh;
            *(short8*)&o_lo[(size_t)node * 128 + l * 8] = ol;
        } else {
            const float* brow = &bias[l * 8];
            floatx4 o0, o1;
            #pragma unroll
            for (int j = 0; j < 4; ++j) {
                o0[j] = acc[j] + brow[j];
                o1[j] = acc[j + 4] + brow[j + 4];
            }
            float* orow = &o_f32[(size_t)node * 128 + l * 8];
            *(floatx4*)orow = o0;
            *(floatx4*)(orow + 4) = o1;
        }
    }
}

// ---------------- launch ----------------
extern "C" void kernel_launch(void* const* d_in, const int* in_sizes, int n_in,
                              void* d_out, int out_size, void* d_ws, size_t ws_size,
                              hipStream_t stream) {
    const float* x   = (const float*)d_in[0];
    const int*   ei  = (const int*)d_in[1];
    const float* W1  = (const float*)d_in[2];
    const float* a1s = (const float*)d_in[3];
    const float* a1d = (const float*)d_in[4];
    const float* b1  = (const float*)d_in[5];
    const float* W2  = (const float*)d_in[6];
    const float* a2s = (const float*)d_in[7];
    const float* a2d = (const float*)d_in[8];
    const float* b2  = (const float*)d_in[9];
    float* out = (float*)d_out;

    const int* e_src = ei;
    const int* e_dst = ei + N_EDGESX;

    char* ws = (char*)d_ws;
    const size_t OFF_XB   = 0;             // bf16 [N][128]
    const size_t OFF_UH   = 12800000;
    const size_t OFF_UL   = 25600000;
    const size_t OFF_G1H  = 38400000;      // bf16 [N][256]
    const size_t OFF_G1L  = 64000000;
    const size_t OFF_H2   = 89600000;      // bf16 [N][128]
    const size_t OFF_W1TH = 102400000;
    const size_t OFF_W1TL = 102465536;
    const size_t OFF_W2TH = 102531072;
    const size_t OFF_W2TL = 102596608;
    const size_t OFF_P1S  = 102662144;
    const size_t OFF_P1D  = 102662656;
    const size_t OFF_AS   = 102663168;
    const size_t OFF_AD   = 102863360;
    const size_t OFF_RP   = 103063552;
    const size_t OFF_CNT  = 103264000;
    const size_t OFF_CUR  = 103464192;
    const size_t OFF_BSUM = 103664384;
    const size_t OFF_ESRC = 103664640;
    const size_t OFF_EDST = 107064640;
    const size_t OFF_EW   = 110464640;

    short* xb   = (short*)(ws + OFF_XB);
    short* uh   = (short*)(ws + OFF_UH);
    short* ul   = (short*)(ws + OFF_UL);
    short* g1h  = (short*)(ws + OFF_G1H);
    short* g1l  = (short*)(ws + OFF_G1L);
    short* h2   = (short*)(ws + OFF_H2);
    short* w1th = (short*)(ws + OFF_W1TH);
    short* w1tl = (short*)(ws + OFF_W1TL);
    short* w2th = (short*)(ws + OFF_W2TH);
    short* w2tl = (short*)(ws + OFF_W2TL);
    float* p1s  = (float*)(ws + OFF_P1S);
    float* p1d  = (float*)(ws + OFF_P1D);
    float* as_b = (float*)(ws + OFF_AS);
    float* ad_b = (float*)(ws + OFF_AD);
    int* row_ptr = (int*)(ws + OFF_RP);
    int* cnt     = (int*)(ws + OFF_CNT);
    int* cursor  = (int*)(ws + OFF_CUR);
    int* bsum    = (int*)(ws + OFF_BSUM);
    int* esrc    = (int*)(ws + OFF_ESRC);
    int* edst    = (int*)(ws + OFF_EDST);
    float* ewb   = (float*)(ws + OFF_EW);

    int egrid = (E_TOT + 255) / 256;
    int ngrid = (N_NODES * 64 + 255) / 256;

    // --- alpha1 (from x) + xb split ---
    gemv_p_kernel<IN_C, HID_C><<<1, 256, 0, stream>>>(W1, a1s, a1d, p1s, p1d);
    alpha_x_kernel<<<ngrid, 256, 0, stream>>>(x, p1s, p1d, as_b, ad_b, xb);

    // --- CSR build (+ fused ew1 in scatter) ---
    hipMemsetAsync(cnt, 0, N_NODES * sizeof(int), stream);
    count_kernel<<<egrid, 256, 0, stream>>>(e_dst, cnt);
    scan_a_kernel<<<NBLK, 1024, 0, stream>>>(cnt, row_ptr, bsum);
    scan_b_kernel<<<1, 64, 0, stream>>>(bsum, row_ptr);
    scan_c_kernel<<<NBLK, 1024, 0, stream>>>(row_ptr, bsum, cursor);
    scatter_kernel<<<egrid, 256, 0, stream>>>(e_src, e_dst, cursor, esrc, edst, as_b, ad_b, ewb);

    // --- weight splits ---
    splitT_kernel<<<(IN_C * HID_C + 255) / 256, 256, 0, stream>>>(W1, w1th, w1tl, IN_C, HID_C);
    splitT_kernel<<<(HID_C * OUT_C + 255) / 256, 256, 0, stream>>>(W2, w2th, w2tl, HID_C, OUT_C);

    // --- layer 1: aggregate x, then transform ---
    aggregate_kernel<0><<<ngrid, 256, 0, stream>>>(xb, ewb, row_ptr, esrc, nullptr, uh, ul, nullptr);
    gemm_mfma<IN_C, 2><<<dim3(HID_C / 64, (N_NODES + 127) / 128), 256, 0, stream>>>(
        uh, ul, w1th, w1tl, HID_C, b1, g1h, g1l);

    // --- layer 2: transform, then aggregate ---
    gemm_mfma<HID_C, 1><<<dim3(OUT_C / 64, (N_NODES + 127) / 128), 256, 0, stream>>>(
        g1h, g1l, w2th, w2tl, OUT_C, nullptr, h2, nullptr);
    alpha_bf16_128<<<ngrid, 256, 0, stream>>>(h2, a2s, a2d, as_b, ad_b);
    ew_kernel<<<egrid, 256, 0, stream>>>(esrc, edst, as_b, ad_b, ewb);
    aggregate_kernel<1><<<ngrid, 256, 0, stream>>>(h2, ewb, row_ptr, esrc, b2, nullptr, nullptr, out);
}

// Round 6
// 365.235 us; speedup vs baseline: 1.7020x; 1.0037x over previous
//
#include <hip/hip_runtime.h>
#include <hip/hip_bf16.h>
#include <math.h>

#define N_NODES 50000
#define N_EDGESX 800000
#define E_TOT   (N_EDGESX + N_NODES)
#define IN_C 128
#define HID_C 256
#define OUT_C 128
#define NEG_SLOPE 0.2f

typedef __attribute__((ext_vector_type(8))) short short8;
typedef __attribute__((ext_vector_type(4))) float floatx4;
typedef __attribute__((ext_vector_type(2))) float floatx2;

__device__ __forceinline__ float bf2f(short s) {
    unsigned u = ((unsigned)(unsigned short)s) << 16;
    float f; __builtin_memcpy(&f, &u, 4); return f;
}
__device__ __forceinline__ short f2bf(float f) {   // RNE
    unsigned u; __builtin_memcpy(&u, &f, 4);
    unsigned r = (u + 0x7FFFu + ((u >> 16) & 1u)) >> 16;
    return (short)r;
}

// ---------------- projected attention vectors: p[k] = sum_n W[k][n]*a[n] ----------------
template<int KROWS, int NCOLS>
__global__ __launch_bounds__(256)
void gemv_p_kernel(const float* __restrict__ W, const float* __restrict__ a_s,
                   const float* __restrict__ a_d, float* __restrict__ ps, float* __restrict__ pd) {
    int t = threadIdx.x;
    int k = t & (KROWS - 1);
    const float* av = (t < KROWS) ? a_s : a_d;
    float* pv = (t < KROWS) ? ps : pd;
    const float* row = W + (size_t)k * NCOLS;
    float s = 0.f;
    for (int n = 0; n < NCOLS; ++n) s += row[n] * av[n];
    pv[k] = s;
}

// ---------------- alpha1 from x + x->bf16 split (fused, one x pass) ----------------
__global__ __launch_bounds__(256)
void alpha_x_kernel(const float* __restrict__ x, const float* __restrict__ ps,
                    const float* __restrict__ pd, float* __restrict__ as_out,
                    float* __restrict__ ad_out, short* __restrict__ xb) {
    int gt = blockIdx.x * blockDim.x + threadIdx.x;
    int node = gt >> 6, lane = gt & 63;
    if (node >= N_NODES) return;
    floatx2 xv = *(const floatx2*)&x[(size_t)node * IN_C + lane * 2];
    floatx2 s2 = *(const floatx2*)&ps[lane * 2];
    floatx2 d2 = *(const floatx2*)&pd[lane * 2];
    float s = xv[0] * s2[0] + xv[1] * s2[1];
    float d = xv[0] * d2[0] + xv[1] * d2[1];
    unsigned pack = (unsigned)(unsigned short)f2bf(xv[0]) | ((unsigned)(unsigned short)f2bf(xv[1]) << 16);
    *(unsigned*)&xb[(size_t)node * IN_C + lane * 2] = pack;
    #pragma unroll
    for (int off = 32; off; off >>= 1) {
        s += __shfl_down(s, off);
        d += __shfl_down(d, off);
    }
    if (lane == 0) { as_out[node] = s; ad_out[node] = d; }
}

// ---------------- CSR build ----------------
__global__ void count_kernel(const int* __restrict__ dst, int* __restrict__ cnt) {
    int i = blockIdx.x * blockDim.x + threadIdx.x;
    if (i < E_TOT) {
        int d = (i < N_EDGESX) ? dst[i] : (i - N_EDGESX);
        atomicAdd(&cnt[d], 1);
    }
}

#define NBLK ((N_NODES + 1023) / 1024)   // 49

__global__ __launch_bounds__(1024)
void scan_a_kernel(const int* __restrict__ cnt, int* __restrict__ row_ptr, int* __restrict__ bsum) {
    __shared__ int buf[1024];
    int tid = threadIdx.x;
    int idx = blockIdx.x * 1024 + tid;
    int v = (idx < N_NODES) ? cnt[idx] : 0;
    buf[tid] = v;
    __syncthreads();
    for (int off = 1; off < 1024; off <<= 1) {
        int t = (tid >= off) ? buf[tid - off] : 0;
        __syncthreads();
        buf[tid] += t;
        __syncthreads();
    }
    if (idx < N_NODES) row_ptr[idx] = buf[tid] - v;
    if (tid == 1023) bsum[blockIdx.x] = buf[1023];
}

__global__ void scan_b_kernel(int* __restrict__ bsum, int* __restrict__ row_ptr) {
    int lane = threadIdx.x;   // 64
    int v = (lane < NBLK) ? bsum[lane] : 0;
    int s = v;
    #pragma unroll
    for (int off = 1; off < 64; off <<= 1) {
        int t = __shfl_up(s, off);
        if (lane >= off) s += t;
    }
    if (lane < NBLK) bsum[lane] = s - v;
    if (lane == 63) row_ptr[N_NODES] = s;
}

__global__ __launch_bounds__(1024)
void scan_c_kernel(int* __restrict__ row_ptr, const int* __restrict__ bsum, int* __restrict__ cursor) {
    int idx = blockIdx.x * 1024 + threadIdx.x;
    if (idx < N_NODES) {
        int v = row_ptr[idx] + bsum[blockIdx.x];
        row_ptr[idx] = v;
        cursor[idx] = v;
    }
}

// scatter: single 4B random write per edge
__global__ void scatter_kernel(const int* __restrict__ src, const int* __restrict__ dst,
                               int* __restrict__ cursor, int* __restrict__ esrc) {
    int i = blockIdx.x * blockDim.x + threadIdx.x;
    if (i < E_TOT) {
        int s, d;
        if (i < N_EDGESX) { s = src[i]; d = dst[i]; }
        else { s = i - N_EDGESX; d = s; }
        int pos = atomicAdd(&cursor[d], 1);
        esrc[pos] = s;
    }
}

// edst from row_ptr (coalesced contiguous-range writes)
__global__ __launch_bounds__(256)
void fill_edst_kernel(const int* __restrict__ row_ptr, int* __restrict__ edst) {
    int gt = blockIdx.x * blockDim.x + threadIdx.x;
    int node = gt >> 6, lane = gt & 63;
    if (node >= N_NODES) return;
    int beg = row_ptr[node], end = row_ptr[node + 1];
    for (int i = beg + lane; i < end; i += 64) edst[i] = node;
}

// ---------------- per-edge logits (coalesced; as/ad gathers are L2-resident) ----------------
__global__ void ew_kernel(const int* __restrict__ esrc, const int* __restrict__ edst,
                          const float* __restrict__ as_in, const float* __restrict__ ad_in,
                          float* __restrict__ ew) {
    int i = blockIdx.x * blockDim.x + threadIdx.x;
    if (i >= E_TOT) return;
    float e = as_in[esrc[i]] + ad_in[edst[i]];
    ew[i] = e > 0.f ? e : NEG_SLOPE * e;
}

// ---------------- W[K][N] -> Wt hi/lo [N][K] ----------------
__global__ void splitT_kernel(const float* __restrict__ W, short* __restrict__ th,
                              short* __restrict__ tl, int K, int N) {
    int i = blockIdx.x * blockDim.x + threadIdx.x;
    if (i >= K * N) return;
    int k = i / N, n = i - k * N;
    float f = W[i];
    short hb = f2bf(f);
    th[n * K + k] = hb;
    tl[n * K + k] = f2bf(f - bf2f(hb));
}

// ---------------- split-bf16 MFMA GEMM ----------------
// C = (Ah+Al)[M,K] @ (Bh+Bl)[K,N], Bt stored [N][K]. BM=128, BN=64, 4 waves.
// OUTMODE 1: plain bf16 -> C0.  OUTMODE 2: relu(v+bias[gc]) -> hi/lo C0/C1.
template<int K, int OUTMODE>
__global__ __launch_bounds__(256)
void gemm_mfma(const short* __restrict__ Ah, const short* __restrict__ Al,
               const short* __restrict__ Bth, const short* __restrict__ Btl,
               int N, const float* __restrict__ bias,
               short* __restrict__ C0, short* __restrict__ C1) {
    __shared__ short Ah_s[128][40];
    __shared__ short Al_s[128][40];
    __shared__ short Bh_s[64][40];
    __shared__ short Bl_s[64][40];
    int tid = threadIdx.x;
    int lane = tid & 63, wave = tid >> 6;
    int wr = wave >> 1, wc = wave & 1;
    int bm = blockIdx.y * 128, bn = blockIdx.x * 64;
    int l15 = lane & 15, kf = (lane >> 4) * 8;

    floatx4 acc[4][2];
    #pragma unroll
    for (int i = 0; i < 4; ++i)
        #pragma unroll
        for (int j = 0; j < 2; ++j) acc[i][j] = (floatx4){0.f, 0.f, 0.f, 0.f};

    int arow = tid >> 1, ac0 = (tid & 1) * 16;
    int brow = tid >> 2, bc0 = (tid & 3) * 8;
    int agm = bm + arow;
    bool aval = agm < N_NODES;

    for (int k0 = 0; k0 < K; k0 += 32) {
        short8 va0 = {0,0,0,0,0,0,0,0}, va1 = va0, vl0 = va0, vl1 = va0;
        if (aval) {
            const short* pa = Ah + (size_t)agm * K + k0 + ac0;
            va0 = *(const short8*)pa; va1 = *(const short8*)(pa + 8);
            const short* pl = Al + (size_t)agm * K + k0 + ac0;
            vl0 = *(const short8*)pl; vl1 = *(const short8*)(pl + 8);
        }
        *(short8*)&Ah_s[arow][ac0]     = va0;
        *(short8*)&Ah_s[arow][ac0 + 8] = va1;
        *(short8*)&Al_s[arow][ac0]     = vl0;
        *(short8*)&Al_s[arow][ac0 + 8] = vl1;
        {
            const short* pb = Bth + (size_t)(bn + brow) * K + k0 + bc0;
            *(short8*)&Bh_s[brow][bc0] = *(const short8*)pb;
            const short* pb2 = Btl + (size_t)(bn + brow) * K + k0 + bc0;
            *(short8*)&Bl_s[brow][bc0] = *(const short8*)pb2;
        }
        __syncthreads();
        short8 afh[4], afl[4], bfh[2], bfl[2];
        #pragma unroll
        for (int mr = 0; mr < 4; ++mr) {
            int r = wr * 64 + mr * 16 + l15;
            afh[mr] = *(const short8*)&Ah_s[r][kf];
            afl[mr] = *(const short8*)&Al_s[r][kf];
        }
        #pragma unroll
        for (int nr = 0; nr < 2; ++nr) {
            int c = wc * 32 + nr * 16 + l15;
            bfh[nr] = *(const short8*)&Bh_s[c][kf];
            bfl[nr] = *(const short8*)&Bl_s[c][kf];
        }
        #pragma unroll
        for (int mr = 0; mr < 4; ++mr)
            #pragma unroll
            for (int nr = 0; nr < 2; ++nr) {
                acc[mr][nr] = __builtin_amdgcn_mfma_f32_16x16x32_bf16(afh[mr], bfh[nr], acc[mr][nr], 0, 0, 0);
                acc[mr][nr] = __builtin_amdgcn_mfma_f32_16x16x32_bf16(afh[mr], bfl[nr], acc[mr][nr], 0, 0, 0);
                acc[mr][nr] = __builtin_amdgcn_mfma_f32_16x16x32_bf16(afl[mr], bfh[nr], acc[mr][nr], 0, 0, 0);
            }
        __syncthreads();
    }
    float bv[2];
    if (OUTMODE == 2) {
        #pragma unroll
        for (int nr = 0; nr < 2; ++nr) bv[nr] = bias[bn + wc * 32 + nr * 16 + l15];
    }
    #pragma unroll
    for (int mr = 0; mr < 4; ++mr) {
        #pragma unroll
        for (int reg = 0; reg < 4; ++reg) {
            int gr = bm + wr * 64 + mr * 16 + (lane >> 4) * 4 + reg;
            if (gr < N_NODES) {
                #pragma unroll
                for (int nr = 0; nr < 2; ++nr) {
                    int gc = bn + wc * 32 + nr * 16 + l15;
                    float v = acc[mr][nr][reg];
                    if (OUTMODE == 1) {
                        C0[(size_t)gr * N + gc] = f2bf(v);
                    } else {
                        v = fmaxf(v + bv[nr], 0.f);
                        short hb = f2bf(v);
                        C0[(size_t)gr * N + gc] = hb;
                        C1[(size_t)gr * N + gc] = f2bf(v - bf2f(hb));
                    }
                }
            }
        }
    }
}

// ---------------- alpha2 from h2 (bf16) ----------------
__global__ __launch_bounds__(256)
void alpha_bf16_128(const short* __restrict__ h, const float* __restrict__ a_src,
                    const float* __restrict__ a_dst, float* __restrict__ as_out,
                    float* __restrict__ ad_out) {
    int gt = blockIdx.x * blockDim.x + threadIdx.x;
    int node = gt >> 6, lane = gt & 63;
    if (node >= N_NODES) return;
    unsigned u = *(const unsigned*)&h[(size_t)node * OUT_C + lane * 2];
    float v0 = bf2f((short)(u & 0xFFFFu));
    float v1 = bf2f((short)(u >> 16));
    floatx2 as2 = *(const floatx2*)&a_src[lane * 2];
    floatx2 ad2 = *(const floatx2*)&a_dst[lane * 2];
    float s = v0 * as2[0] + v1 * as2[1];
    float d = v0 * ad2[0] + v1 * ad2[1];
    #pragma unroll
    for (int off = 32; off; off >>= 1) {
        s += __shfl_down(s, off);
        d += __shfl_down(d, off);
    }
    if (lane == 0) { as_out[node] = s; ad_out[node] = d; }
}

// ---------------- fused segment softmax + aggregate (F=128 bf16 rows) ----------------
// One wave/node: online (max,sum); gather unrolled 2x -> 8 row-loads in flight.
// OUT==0: hi/lo bf16 out. OUT==1: fp32 out + bias (final).
template<int OUT>
__global__ __launch_bounds__(256)
void aggregate_kernel(const short* __restrict__ h, const float* __restrict__ ew,
                      const int* __restrict__ row_ptr, const int* __restrict__ esrc,
                      const float* __restrict__ bias,
                      short* __restrict__ o_hi, short* __restrict__ o_lo,
                      float* __restrict__ o_f32) {
    int gt = blockIdx.x * blockDim.x + threadIdx.x;
    int node = gt >> 6, lane = gt & 63;
    if (node >= N_NODES) return;
    int beg = row_ptr[node], end = row_ptr[node + 1];

    float ml = -1e30f, zl = 0.f;
    for (int i = beg + lane; i < end; i += 64) {
        float e = ew[i];
        float mn = fmaxf(ml, e);
        zl = zl * __expf(ml - mn) + __expf(e - mn);
        ml = mn;
    }
    #pragma unroll
    for (int off = 32; off; off >>= 1) {
        float mo = __shfl_xor(ml, off);
        float zo = __shfl_xor(zl, off);
        float mn = fmaxf(ml, mo);
        zl = zl * __expf(ml - mn) + zo * __expf(mo - mn);
        ml = mn;
    }
    float m = ml;
    float inv_z = 1.f / zl;

    int grp = lane >> 4, l = lane & 15;
    float acc[8] = {};
    int i = beg;
    for (; i + 4 < end; i += 8) {
        int e0 = i + grp;
        int e1 = i + 4 + grp;
        bool v1 = e1 < end;
        int s0 = esrc[e0];
        int s1 = esrc[v1 ? e1 : beg];
        float w0 = __expf(ew[e0] - m) * inv_z;
        float w1 = v1 ? __expf(ew[e1] - m) * inv_z : 0.f;
        short8 hv0 = *(const short8*)&h[(size_t)s0 * 128 + l * 8];
        short8 hv1 = *(const short8*)&h[(size_t)s1 * 128 + l * 8];
        #pragma unroll
        for (int j = 0; j < 8; ++j) acc[j] += w0 * bf2f(hv0[j]);
        #pragma unroll
        for (int j = 0; j < 8; ++j) acc[j] += w1 * bf2f(hv1[j]);
    }
    if (i < end) {
        int e = i + grp;
        bool v = e < end;
        int s = esrc[v ? e : beg];
        float w = v ? __expf(ew[e] - m) * inv_z : 0.f;
        short8 hv = *(const short8*)&h[(size_t)s * 128 + l * 8];
        #pragma unroll
        for (int j = 0; j < 8; ++j) acc[j] += w * bf2f(hv[j]);
    }
    #pragma unroll
    for (int j = 0; j < 8; ++j) {
        acc[j] += __shfl_xor(acc[j], 16);
        acc[j] += __shfl_xor(acc[j], 32);
    }

    if (lane < 16) {
        if (OUT == 0) {
            short8 oh, ol;
            #pragma unroll
            for (int j = 0; j < 8; ++j) {
                short hb = f2bf(acc[j]);
                oh[j] = hb;
                ol[j] = f2bf(acc[j] - bf2f(hb));
            }
            *(short8*)&o_hi[(size_t)node * 128 + l * 8] = oh;
            *(short8*)&o_lo[(size_t)node * 128 + l * 8] = ol;
        } else {
            const float* brow = &bias[l * 8];
            floatx4 o0, o1;
            #pragma unroll
            for (int j = 0; j < 4; ++j) {
                o0[j] = acc[j] + brow[j];
                o1[j] = acc[j + 4] + brow[j + 4];
            }
            float* orow = &o_f32[(size_t)node * 128 + l * 8];
            *(floatx4*)orow = o0;
            *(floatx4*)(orow + 4) = o1;
        }
    }
}

// ---------------- launch ----------------
extern "C" void kernel_launch(void* const* d_in, const int* in_sizes, int n_in,
                              void* d_out, int out_size, void* d_ws, size_t ws_size,
                              hipStream_t stream) {
    const float* x   = (const float*)d_in[0];
    const int*   ei  = (const int*)d_in[1];
    const float* W1  = (const float*)d_in[2];
    const float* a1s = (const float*)d_in[3];
    const float* a1d = (const float*)d_in[4];
    const float* b1  = (const float*)d_in[5];
    const float* W2  = (const float*)d_in[6];
    const float* a2s = (const float*)d_in[7];
    const float* a2d = (const float*)d_in[8];
    const float* b2  = (const float*)d_in[9];
    float* out = (float*)d_out;

    const int* e_src = ei;
    const int* e_dst = ei + N_EDGESX;

    char* ws = (char*)d_ws;
    const size_t OFF_XB   = 0;             // bf16 [N][128]
    const size_t OFF_UH   = 12800000;
    const size_t OFF_UL   = 25600000;
    const size_t OFF_G1H  = 38400000;      // bf16 [N][256]
    const size_t OFF_G1L  = 64000000;
    const size_t OFF_H2   = 89600000;      // bf16 [N][128]
    const size_t OFF_W1TH = 102400000;
    const size_t OFF_W1TL = 102465536;
    const size_t OFF_W2TH = 102531072;
    const size_t OFF_W2TL = 102596608;
    const size_t OFF_P1S  = 102662144;
    const size_t OFF_P1D  = 102662656;
    const size_t OFF_AS   = 102663168;
    const size_t OFF_AD   = 102863360;
    const size_t OFF_RP   = 103063552;
    const size_t OFF_CNT  = 103264000;
    const size_t OFF_CUR  = 103464192;
    const size_t OFF_BSUM = 103664384;
    const size_t OFF_ESRC = 103664640;
    const size_t OFF_EDST = 107064640;
    const size_t OFF_EW   = 110464640;

    short* xb   = (short*)(ws + OFF_XB);
    short* uh   = (short*)(ws + OFF_UH);
    short* ul   = (short*)(ws + OFF_UL);
    short* g1h  = (short*)(ws + OFF_G1H);
    short* g1l  = (short*)(ws + OFF_G1L);
    short* h2   = (short*)(ws + OFF_H2);
    short* w1th = (short*)(ws + OFF_W1TH);
    short* w1tl = (short*)(ws + OFF_W1TL);
    short* w2th = (short*)(ws + OFF_W2TH);
    short* w2tl = (short*)(ws + OFF_W2TL);
    float* p1s  = (float*)(ws + OFF_P1S);
    float* p1d  = (float*)(ws + OFF_P1D);
    float* as_b = (float*)(ws + OFF_AS);
    float* ad_b = (float*)(ws + OFF_AD);
    int* row_ptr = (int*)(ws + OFF_RP);
    int* cnt     = (int*)(ws + OFF_CNT);
    int* cursor  = (int*)(ws + OFF_CUR);
    int* bsum    = (int*)(ws + OFF_BSUM);
    int* esrc    = (int*)(ws + OFF_ESRC);
    int* edst    = (int*)(ws + OFF_EDST);
    float* ewb   = (float*)(ws + OFF_EW);

    int egrid = (E_TOT + 255) / 256;
    int ngrid = (N_NODES * 64 + 255) / 256;

    // --- alpha1 (from x) + xb split ---
    gemv_p_kernel<IN_C, HID_C><<<1, 256, 0, stream>>>(W1, a1s, a1d, p1s, p1d);
    alpha_x_kernel<<<ngrid, 256, 0, stream>>>(x, p1s, p1d, as_b, ad_b, xb);

    // --- CSR build ---
    hipMemsetAsync(cnt, 0, N_NODES * sizeof(int), stream);
    count_kernel<<<egrid, 256, 0, stream>>>(e_dst, cnt);
    scan_a_kernel<<<NBLK, 1024, 0, stream>>>(cnt, row_ptr, bsum);
    scan_b_kernel<<<1, 64, 0, stream>>>(bsum, row_ptr);
    scan_c_kernel<<<NBLK, 1024, 0, stream>>>(row_ptr, bsum, cursor);
    scatter_kernel<<<egrid, 256, 0, stream>>>(e_src, e_dst, cursor, esrc);
    fill_edst_kernel<<<ngrid, 256, 0, stream>>>(row_ptr, edst);
    ew_kernel<<<egrid, 256, 0, stream>>>(esrc, edst, as_b, ad_b, ewb);

    // --- weight splits ---
    splitT_kernel<<<(IN_C * HID_C + 255) / 256, 256, 0, stream>>>(W1, w1th, w1tl, IN_C, HID_C);
    splitT_kernel<<<(HID_C * OUT_C + 255) / 256, 256, 0, stream>>>(W2, w2th, w2tl, HID_C, OUT_C);

    // --- layer 1: aggregate x, then transform ---
    aggregate_kernel<0><<<ngrid, 256, 0, stream>>>(xb, ewb, row_ptr, esrc, nullptr, uh, ul, nullptr);
    gemm_mfma<IN_C, 2><<<dim3(HID_C / 64, (N_NODES + 127) / 128), 256, 0, stream>>>(
        uh, ul, w1th, w1tl, HID_C, b1, g1h, g1l);

    // --- layer 2: transform, then aggregate ---
    gemm_mfma<HID_C, 1><<<dim3(OUT_C / 64, (N_NODES + 127) / 128), 256, 0, stream>>>(
        g1h, g1l, w2th, w2tl, OUT_C, nullptr, h2, nullptr);
    alpha_bf16_128<<<ngrid, 256, 0, stream>>>(h2, a2s, a2d, as_b, ad_b);
    ew_kernel<<<egrid, 256, 0, stream>>>(esrc, edst, as_b, ad_b, ewb);
    aggregate_kernel<1><<<ngrid, 256, 0, stream>>>(h2, ewb, row_ptr, esrc, b2, nullptr, nullptr, out);
}

// Round 8
// 309.245 us; speedup vs baseline: 2.0101x; 1.1811x over previous
//
#include <hip/hip_runtime.h>
#include <hip/hip_bf16.h>
#include <math.h>

#define N_NODES 50000
#define N_EDGESX 800000
#define E_TOT   (N_EDGESX + N_NODES)
#define IN_C 128
#define HID_C 256
#define OUT_C 128
#define NEG_SLOPE 0.2f

// bucketed counting sort params
#define NPB   100                         // nodes per bucket
#define NBUCK ((N_NODES + NPB - 1) / NPB) // 500
#define BCAP  2560                        // max edges per bucket (mean ~1700, +21 sigma)
#define EPB   4096                        // edges per binA block
#define NABLK ((E_TOT + EPB - 1) / EPB)   // 208

typedef __attribute__((ext_vector_type(8))) short short8;
typedef __attribute__((ext_vector_type(4))) float floatx4;
typedef __attribute__((ext_vector_type(2))) float floatx2;

__device__ __forceinline__ float bf2f(short s) {
    unsigned u = ((unsigned)(unsigned short)s) << 16;
    float f; __builtin_memcpy(&f, &u, 4); return f;
}
__device__ __forceinline__ short f2bf(float f) {   // RNE
    unsigned u; __builtin_memcpy(&u, &f, 4);
    unsigned r = (u + 0x7FFFu + ((u >> 16) & 1u)) >> 16;
    return (short)r;
}

// ---------------- projected attention vectors: p[k] = sum_n W[k][n]*a[n] ----------------
template<int KROWS, int NCOLS>
__global__ __launch_bounds__(256)
void gemv_p_kernel(const float* __restrict__ W, const float* __restrict__ a_s,
                   const float* __restrict__ a_d, float* __restrict__ ps, float* __restrict__ pd) {
    int t = threadIdx.x;
    int k = t & (KROWS - 1);
    const float* av = (t < KROWS) ? a_s : a_d;
    float* pv = (t < KROWS) ? ps : pd;
    const float* row = W + (size_t)k * NCOLS;
    float s = 0.f;
    for (int n = 0; n < NCOLS; ++n) s += row[n] * av[n];
    pv[k] = s;
}

// ---------------- alpha1 from x + x->bf16 split (fused, one x pass) ----------------
__global__ __launch_bounds__(256)
void alpha_x_kernel(const float* __restrict__ x, const float* __restrict__ ps,
                    const float* __restrict__ pd, float* __restrict__ as_out,
                    float* __restrict__ ad_out, short* __restrict__ xb) {
    int gt = blockIdx.x * blockDim.x + threadIdx.x;
    int node = gt >> 6, lane = gt & 63;
    if (node >= N_NODES) return;
    floatx2 xv = *(const floatx2*)&x[(size_t)node * IN_C + lane * 2];
    floatx2 s2 = *(const floatx2*)&ps[lane * 2];
    floatx2 d2 = *(const floatx2*)&pd[lane * 2];
    float s = xv[0] * s2[0] + xv[1] * s2[1];
    float d = xv[0] * d2[0] + xv[1] * d2[1];
    unsigned pack = (unsigned)(unsigned short)f2bf(xv[0]) | ((unsigned)(unsigned short)f2bf(xv[1]) << 16);
    *(unsigned*)&xb[(size_t)node * IN_C + lane * 2] = pack;
    #pragma unroll
    for (int off = 32; off; off >>= 1) {
        s += __shfl_down(s, off);
        d += __shfl_down(d, off);
    }
    if (lane == 0) { as_out[node] = s; ad_out[node] = d; }
}

// ---------------- bucketed CSR build ----------------
// A: bin edges into per-bucket staging. LDS histogram + one global atomic per (block,bucket).
__global__ __launch_bounds__(256)
void binA_kernel(const int* __restrict__ src, const int* __restrict__ dst,
                 int* __restrict__ bcnt, int2* __restrict__ stage) {
    __shared__ int hist[NBUCK];
    __shared__ int base[NBUCK];
    for (int b = threadIdx.x; b < NBUCK; b += 256) hist[b] = 0;
    __syncthreads();
    int e0 = blockIdx.x * EPB;
    int e1 = min(e0 + EPB, E_TOT);
    for (int i = e0 + threadIdx.x; i < e1; i += 256) {
        int d = (i < N_EDGESX) ? dst[i] : (i - N_EDGESX);
        atomicAdd(&hist[d / NPB], 1);
    }
    __syncthreads();
    for (int b = threadIdx.x; b < NBUCK; b += 256) {
        int c = hist[b];
        base[b] = c ? atomicAdd(&bcnt[b], c) : 0;
        hist[b] = 0;
    }
    __syncthreads();
    for (int i = e0 + threadIdx.x; i < e1; i += 256) {
        int s, d;
        if (i < N_EDGESX) { s = src[i]; d = dst[i]; }
        else { s = i - N_EDGESX; d = s; }
        int b = d / NPB;
        int off = base[b] + atomicAdd(&hist[b], 1);
        if (off < BCAP) stage[(size_t)b * BCAP + off] = make_int2(s, d);
    }
}

// B: per-bucket per-node counts (LDS), coalesced cnt writes
__global__ __launch_bounds__(128)
void bucket_count_kernel(const int* __restrict__ bcnt, const int2* __restrict__ stage,
                         int* __restrict__ cnt) {
    __shared__ int lc[NPB];
    int b = blockIdx.x;
    for (int t = threadIdx.x; t < NPB; t += 128) lc[t] = 0;
    __syncthreads();
    int n = min(bcnt[b], BCAP);
    const int2* sp = stage + (size_t)b * BCAP;
    for (int i = threadIdx.x; i < n; i += 128)
        atomicAdd(&lc[sp[i].y - b * NPB], 1);
    __syncthreads();
    int nb = b * NPB;
    for (int t = threadIdx.x; t < NPB; t += 128)
        if (nb + t < N_NODES) cnt[nb + t] = lc[t];
}

// C: scatter esrc via LDS cursors + fused layer-1 edge logits
__global__ __launch_bounds__(128)
void bucket_scatter_kernel(const int* __restrict__ bcnt, const int2* __restrict__ stage,
                           const int* __restrict__ row_ptr, const float* __restrict__ as_in,
                           const float* __restrict__ ad_in, int* __restrict__ esrc,
                           float* __restrict__ ew) {
    __shared__ int cur[NPB];
    __shared__ float adl[NPB];
    int b = blockIdx.x;
    int nb = b * NPB;
    for (int t = threadIdx.x; t < NPB; t += 128) {
        int node = nb + t;
        cur[t] = (node < N_NODES) ? row_ptr[node] : 0;
        adl[t] = (node < N_NODES) ? ad_in[node] : 0.f;
    }
    __syncthreads();
    int n = min(bcnt[b], BCAP);
    const int2* sp = stage + (size_t)b * BCAP;
    for (int i = threadIdx.x; i < n; i += 128) {
        int2 e = sp[i];
        int li = e.y - nb;
        int pos = atomicAdd(&cur[li], 1);
        esrc[pos] = e.x;
        float v = as_in[e.x] + adl[li];
        ew[pos] = v > 0.f ? v : NEG_SLOPE * v;
    }
}

#define NBLK ((N_NODES + 1023) / 1024)   // 49

__global__ __launch_bounds__(1024)
void scan_a_kernel(const int* __restrict__ cnt, int* __restrict__ row_ptr, int* __restrict__ bsum) {
    __shared__ int buf[1024];
    int tid = threadIdx.x;
    int idx = blockIdx.x * 1024 + tid;
    int v = (idx < N_NODES) ? cnt[idx] : 0;
    buf[tid] = v;
    __syncthreads();
    for (int off = 1; off < 1024; off <<= 1) {
        int t = (tid >= off) ? buf[tid - off] : 0;
        __syncthreads();
        buf[tid] += t;
        __syncthreads();
    }
    if (idx < N_NODES) row_ptr[idx] = buf[tid] - v;
    if (tid == 1023) bsum[blockIdx.x] = buf[1023];
}

__global__ void scan_b_kernel(int* __restrict__ bsum, int* __restrict__ row_ptr) {
    int lane = threadIdx.x;   // 64
    int v = (lane < NBLK) ? bsum[lane] : 0;
    int s = v;
    #pragma unroll
    for (int off = 1; off < 64; off <<= 1) {
        int t = __shfl_up(s, off);
        if (lane >= off) s += t;
    }
    if (lane < NBLK) bsum[lane] = s - v;
    if (lane == 63) row_ptr[N_NODES] = s;
}

__global__ __launch_bounds__(1024)
void scan_c_kernel(int* __restrict__ row_ptr, const int* __restrict__ bsum) {
    int idx = blockIdx.x * 1024 + threadIdx.x;
    if (idx < N_NODES) row_ptr[idx] += bsum[blockIdx.x];
}

// edst from row_ptr (coalesced contiguous-range writes)
__global__ __launch_bounds__(256)
void fill_edst_kernel(const int* __restrict__ row_ptr, int* __restrict__ edst) {
    int gt = blockIdx.x * blockDim.x + threadIdx.x;
    int node = gt >> 6, lane = gt & 63;
    if (node >= N_NODES) return;
    int beg = row_ptr[node], end = row_ptr[node + 1];
    for (int i = beg + lane; i < end; i += 64) edst[i] = node;
}

// ---------------- per-edge logits for layer 2 ----------------
__global__ void ew_kernel(const int* __restrict__ esrc, const int* __restrict__ edst,
                          const float* __restrict__ as_in, const float* __restrict__ ad_in,
                          float* __restrict__ ew) {
    int i = blockIdx.x * blockDim.x + threadIdx.x;
    if (i >= E_TOT) return;
    float e = as_in[esrc[i]] + ad_in[edst[i]];
    ew[i] = e > 0.f ? e : NEG_SLOPE * e;
}

// ---------------- W[K][N] -> Wt hi/lo [N][K] ----------------
__global__ void splitT_kernel(const float* __restrict__ W, short* __restrict__ th,
                              short* __restrict__ tl, int K, int N) {
    int i = blockIdx.x * blockDim.x + threadIdx.x;
    if (i >= K * N) return;
    int k = i / N, n = i - k * N;
    float f = W[i];
    short hb = f2bf(f);
    th[n * K + k] = hb;
    tl[n * K + k] = f2bf(f - bf2f(hb));
}

// ---------------- split-bf16 MFMA GEMM ----------------
// C = (Ah+Al)[M,K] @ (Bh+Bl)[K,N], Bt stored [N][K]. BM=128, BN=64, 4 waves.
// OUTMODE 1: plain bf16 -> C0.  OUTMODE 2: relu(v+bias[gc]) -> hi/lo C0/C1.
template<int K, int OUTMODE>
__global__ __launch_bounds__(256)
void gemm_mfma(const short* __restrict__ Ah, const short* __restrict__ Al,
               const short* __restrict__ Bth, const short* __restrict__ Btl,
               int N, const float* __restrict__ bias,
               short* __restrict__ C0, short* __restrict__ C1) {
    __shared__ short Ah_s[128][40];
    __shared__ short Al_s[128][40];
    __shared__ short Bh_s[64][40];
    __shared__ short Bl_s[64][40];
    int tid = threadIdx.x;
    int lane = tid & 63, wave = tid >> 6;
    int wr = wave >> 1, wc = wave & 1;
    int bm = blockIdx.y * 128, bn = blockIdx.x * 64;
    int l15 = lane & 15, kf = (lane >> 4) * 8;

    floatx4 acc[4][2];
    #pragma unroll
    for (int i = 0; i < 4; ++i)
        #pragma unroll
        for (int j = 0; j < 2; ++j) acc[i][j] = (floatx4){0.f, 0.f, 0.f, 0.f};

    int arow = tid >> 1, ac0 = (tid & 1) * 16;
    int brow = tid >> 2, bc0 = (tid & 3) * 8;
    int agm = bm + arow;
    bool aval = agm < N_NODES;

    for (int k0 = 0; k0 < K; k0 += 32) {
        short8 va0 = {0,0,0,0,0,0,0,0}, va1 = va0, vl0 = va0, vl1 = va0;
        if (aval) {
            const short* pa = Ah + (size_t)agm * K + k0 + ac0;
            va0 = *(const short8*)pa; va1 = *(const short8*)(pa + 8);
            const short* pl = Al + (size_t)agm * K + k0 + ac0;
            vl0 = *(const short8*)pl; vl1 = *(const short8*)(pl + 8);
        }
        *(short8*)&Ah_s[arow][ac0]     = va0;
        *(short8*)&Ah_s[arow][ac0 + 8] = va1;
        *(short8*)&Al_s[arow][ac0]     = vl0;
        *(short8*)&Al_s[arow][ac0 + 8] = vl1;
        {
            const short* pb = Bth + (size_t)(bn + brow) * K + k0 + bc0;
            *(short8*)&Bh_s[brow][bc0] = *(const short8*)pb;
            const short* pb2 = Btl + (size_t)(bn + brow) * K + k0 + bc0;
            *(short8*)&Bl_s[brow][bc0] = *(const short8*)pb2;
        }
        __syncthreads();
        short8 afh[4], afl[4], bfh[2], bfl[2];
        #pragma unroll
        for (int mr = 0; mr < 4; ++mr) {
            int r = wr * 64 + mr * 16 + l15;
            afh[mr] = *(const short8*)&Ah_s[r][kf];
            afl[mr] = *(const short8*)&Al_s[r][kf];
        }
        #pragma unroll
        for (int nr = 0; nr < 2; ++nr) {
            int c = wc * 32 + nr * 16 + l15;
            bfh[nr] = *(const short8*)&Bh_s[c][kf];
            bfl[nr] = *(const short8*)&Bl_s[c][kf];
        }
        #pragma unroll
        for (int mr = 0; mr < 4; ++mr)
            #pragma unroll
            for (int nr = 0; nr < 2; ++nr) {
                acc[mr][nr] = __builtin_amdgcn_mfma_f32_16x16x32_bf16(afh[mr], bfh[nr], acc[mr][nr], 0, 0, 0);
                acc[mr][nr] = __builtin_amdgcn_mfma_f32_16x16x32_bf16(afh[mr], bfl[nr], acc[mr][nr], 0, 0, 0);
                acc[mr][nr] = __builtin_amdgcn_mfma_f32_16x16x32_bf16(afl[mr], bfh[nr], acc[mr][nr], 0, 0, 0);
            }
        __syncthreads();
    }
    float bv[2];
    if (OUTMODE == 2) {
        #pragma unroll
        for (int nr = 0; nr < 2; ++nr) bv[nr] = bias[bn + wc * 32 + nr * 16 + l15];
    }
    #pragma unroll
    for (int mr = 0; mr < 4; ++mr) {
        #pragma unroll
        for (int reg = 0; reg < 4; ++reg) {
            int gr = bm + wr * 64 + mr * 16 + (lane >> 4) * 4 + reg;
            if (gr < N_NODES) {
                #pragma unroll
                for (int nr = 0; nr < 2; ++nr) {
                    int gc = bn + wc * 32 + nr * 16 + l15;
                    float v = acc[mr][nr][reg];
                    if (OUTMODE == 1) {
                        C0[(size_t)gr * N + gc] = f2bf(v);
                    } else {
                        v = fmaxf(v + bv[nr], 0.f);
                        short hb = f2bf(v);
                        C0[(size_t)gr * N + gc] = hb;
                        C1[(size_t)gr * N + gc] = f2bf(v - bf2f(hb));
                    }
                }
            }
        }
    }
}

// ---------------- alpha2 from h2 (bf16) ----------------
__global__ __launch_bounds__(256)
void alpha_bf16_128(const short* __restrict__ h, const float* __restrict__ a_src,
                    const float* __restrict__ a_dst, float* __restrict__ as_out,
                    float* __restrict__ ad_out) {
    int gt = blockIdx.x * blockDim.x + threadIdx.x;
    int node = gt >> 6, lane = gt & 63;
    if (node >= N_NODES) return;
    unsigned u = *(const unsigned*)&h[(size_t)node * OUT_C + lane * 2];
    float v0 = bf2f((short)(u & 0xFFFFu));
    float v1 = bf2f((short)(u >> 16));
    floatx2 as2 = *(const floatx2*)&a_src[lane * 2];
    floatx2 ad2 = *(const floatx2*)&a_dst[lane * 2];
    float s = v0 * as2[0] + v1 * as2[1];
    float d = v0 * ad2[0] + v1 * ad2[1];
    #pragma unroll
    for (int off = 32; off; off >>= 1) {
        s += __shfl_down(s, off);
        d += __shfl_down(d, off);
    }
    if (lane == 0) { as_out[node] = s; ad_out[node] = d; }
}

// ---------------- fused segment softmax + aggregate (F=128 bf16 rows) ----------------
// One wave/node: online (max,sum); gather unrolled 2x -> 8 row-loads in flight.
// OUT==0: hi/lo bf16 out. OUT==1: fp32 out + bias (final).
template<int OUT>
__global__ __launch_bounds__(256)
void aggregate_kernel(const short* __restrict__ h, const float* __restrict__ ew,
                      const int* __restrict__ row_ptr, const int* __restrict__ esrc,
                      const float* __restrict__ bias,
                      short* __restrict__ o_hi, short* __restrict__ o_lo,
                      float* __restrict__ o_f32) {
    int gt = blockIdx.x * blockDim.x + threadIdx.x;
    int node = gt >> 6, lane = gt & 63;
    if (node >= N_NODES) return;
    int beg = row_ptr[node], end = row_ptr[node + 1];

    float ml = -1e30f, zl = 0.f;
    for (int i = beg + lane; i < end; i += 64) {
        float e = ew[i];
        float mn = fmaxf(ml, e);
        zl = zl * __expf(ml - mn) + __expf(e - mn);
        ml = mn;
    }
    #pragma unroll
    for (int off = 32; off; off >>= 1) {
        float mo = __shfl_xor(ml, off);
        float zo = __shfl_xor(zl, off);
        float mn = fmaxf(ml, mo);
        zl = zl * __expf(ml - mn) + zo * __expf(mo - mn);
        ml = mn;
    }
    float m = ml;
    float inv_z = 1.f / zl;

    int grp = lane >> 4, l = lane & 15;
    float acc[8] = {};
    int i = beg;
    for (; i + 4 < end; i += 8) {
        int e0 = i + grp;
        int e1 = i + 4 + grp;
        bool v1 = e1 < end;
        int s0 = esrc[e0];
        int s1 = esrc[v1 ? e1 : beg];
        float w0 = __expf(ew[e0] - m) * inv_z;
        float w1 = v1 ? __expf(ew[e1] - m) * inv_z : 0.f;
        short8 hv0 = *(const short8*)&h[(size_t)s0 * 128 + l * 8];
        short8 hv1 = *(const short8*)&h[(size_t)s1 * 128 + l * 8];
        #pragma unroll
        for (int j = 0; j < 8; ++j) acc[j] += w0 * bf2f(hv0[j]);
        #pragma unroll
        for (int j = 0; j < 8; ++j) acc[j] += w1 * bf2f(hv1[j]);
    }
    if (i < end) {
        int e = i + grp;
        bool v = e < end;
        int s = esrc[v ? e : beg];
        float w = v ? __expf(ew[e] - m) * inv_z : 0.f;
        short8 hv = *(const short8*)&h[(size_t)s * 128 + l * 8];
        #pragma unroll
        for (int j = 0; j < 8; ++j) acc[j] += w * bf2f(hv[j]);
    }
    #pragma unroll
    for (int j = 0; j < 8; ++j) {
        acc[j] += __shfl_xor(acc[j], 16);
        acc[j] += __shfl_xor(acc[j], 32);
    }

    if (lane < 16) {
        if (OUT == 0) {
            short8 oh, ol;
            #pragma unroll
            for (int j = 0; j < 8; ++j) {
                short hb = f2bf(acc[j]);
                oh[j] = hb;
                ol[j] = f2bf(acc[j] - bf2f(hb));
            }
            *(short8*)&o_hi[(size_t)node * 128 + l * 8] = oh;
            *(short8*)&o_lo[(size_t)node * 128 + l * 8] = ol;
        } else {
            const float* brow = &bias[l * 8];
            floatx4 o0, o1;
            #pragma unroll
            for (int j = 0; j < 4; ++j) {
                o0[j] = acc[j] + brow[j];
                o1[j] = acc[j + 4] + brow[j + 4];
            }
            float* orow = &o_f32[(size_t)node * 128 + l * 8];
            *(floatx4*)orow = o0;
            *(floatx4*)(orow + 4) = o1;
        }
    }
}

// ---------------- launch ----------------
extern "C" void kernel_launch(void* const* d_in, const int* in_sizes, int n_in,
                              void* d_out, int out_size, void* d_ws, size_t ws_size,
                              hipStream_t stream) {
    const float* x   = (const float*)d_in[0];
    const int*   ei  = (const int*)d_in[1];
    const float* W1  = (const float*)d_in[2];
    const float* a1s = (const float*)d_in[3];
    const float* a1d = (const float*)d_in[4];
    const float* b1  = (const float*)d_in[5];
    const float* W2  = (const float*)d_in[6];
    const float* a2s = (const float*)d_in[7];
    const float* a2d = (const float*)d_in[8];
    const float* b2  = (const float*)d_in[9];
    float* out = (float*)d_out;

    const int* e_src = ei;
    const int* e_dst = ei + N_EDGESX;

    char* ws = (char*)d_ws;
    const size_t OFF_XB    = 0;             // bf16 [N][128]
    const size_t OFF_UH    = 12800000;
    const size_t OFF_UL    = 25600000;
    const size_t OFF_G1H   = 38400000;      // bf16 [N][256]
    const size_t OFF_G1L   = 64000000;
    const size_t OFF_H2    = 89600000;      // bf16 [N][128]
    const size_t OFF_W1TH  = 102400000;
    const size_t OFF_W1TL  = 102465536;
    const size_t OFF_W2TH  = 102531072;
    const size_t OFF_W2TL  = 102596608;
    const size_t OFF_P1S   = 102662144;
    const size_t OFF_P1D   = 102662656;
    const size_t OFF_AS    = 102663168;
    const size_t OFF_AD    = 102863360;
    const size_t OFF_RP    = 103063552;
    const size_t OFF_CNT   = 103264000;
    const size_t OFF_BSUM  = 103464192;
    const size_t OFF_BCNT  = 103464448;     // NBUCK ints
    const size_t OFF_ESRC  = 103466496;
    const size_t OFF_EDST  = 106866496;
    const size_t OFF_EW    = 110266496;
    const size_t OFF_STAGE = 113666496;     // int2 [NBUCK][BCAP] = 10.24 MB

    short* xb   = (short*)(ws + OFF_XB);
    short* uh   = (short*)(ws + OFF_UH);
    short* ul   = (short*)(ws + OFF_UL);
    short* g1h  = (short*)(ws + OFF_G1H);
    short* g1l  = (short*)(ws + OFF_G1L);
    short* h2   = (short*)(ws + OFF_H2);
    short* w1th = (short*)(ws + OFF_W1TH);
    short* w1tl = (short*)(ws + OFF_W1TL);
    short* w2th = (short*)(ws + OFF_W2TH);
    short* w2tl = (short*)(ws + OFF_W2TL);
    float* p1s  = (float*)(ws + OFF_P1S);
    float* p1d  = (float*)(ws + OFF_P1D);
    float* as_b = (float*)(ws + OFF_AS);
    float* ad_b = (float*)(ws + OFF_AD);
    int* row_ptr = (int*)(ws + OFF_RP);
    int* cnt     = (int*)(ws + OFF_CNT);
    int* bsum    = (int*)(ws + OFF_BSUM);
    int* bcnt    = (int*)(ws + OFF_BCNT);
    int* esrc    = (int*)(ws + OFF_ESRC);
    int* edst    = (int*)(ws + OFF_EDST);
    float* ewb   = (float*)(ws + OFF_EW);
    int2* stage  = (int2*)(ws + OFF_STAGE);

    int egrid = (E_TOT + 255) / 256;
    int ngrid = (N_NODES * 64 + 255) / 256;

    // --- alpha1 (from x) + xb split ---
    gemv_p_kernel<IN_C, HID_C><<<1, 256, 0, stream>>>(W1, a1s, a1d, p1s, p1d);
    alpha_x_kernel<<<ngrid, 256, 0, stream>>>(x, p1s, p1d, as_b, ad_b, xb);

    // --- bucketed CSR build ---
    hipMemsetAsync(bcnt, 0, NBUCK * sizeof(int), stream);
    binA_kernel<<<NABLK, 256, 0, stream>>>(e_src, e_dst, bcnt, stage);
    bucket_count_kernel<<<NBUCK, 128, 0, stream>>>(bcnt, stage, cnt);
    scan_a_kernel<<<NBLK, 1024, 0, stream>>>(cnt, row_ptr, bsum);
    scan_b_kernel<<<1, 64, 0, stream>>>(bsum, row_ptr);
    scan_c_kernel<<<NBLK, 1024, 0, stream>>>(row_ptr, bsum);
    bucket_scatter_kernel<<<NBUCK, 128, 0, stream>>>(bcnt, stage, row_ptr, as_b, ad_b, esrc, ewb);
    fill_edst_kernel<<<ngrid, 256, 0, stream>>>(row_ptr, edst);

    // --- weight splits ---
    splitT_kernel<<<(IN_C * HID_C + 255) / 256, 256, 0, stream>>>(W1, w1th, w1tl, IN_C, HID_C);
    splitT_kernel<<<(HID_C * OUT_C + 255) / 256, 256, 0, stream>>>(W2, w2th, w2tl, HID_C, OUT_C);

    // --- layer 1: aggregate x, then transform ---
    aggregate_kernel<0><<<ngrid, 256, 0, stream>>>(xb, ewb, row_ptr, esrc, nullptr, uh, ul, nullptr);
    gemm_mfma<IN_C, 2><<<dim3(HID_C / 64, (N_NODES + 127) / 128), 256, 0, stream>>>(
        uh, ul, w1th, w1tl, HID_C, b1, g1h, g1l);

    // --- layer 2: transform, then aggregate ---
    gemm_mfma<HID_C, 1><<<dim3(OUT_C / 64, (N_NODES + 127) / 128), 256, 0, stream>>>(
        g1h, g1l, w2th, w2tl, OUT_C, nullptr, h2, nullptr);
    alpha_bf16_128<<<ngrid, 256, 0, stream>>>(h2, a2s, a2d, as_b, ad_b);
    ew_kernel<<<egrid, 256, 0, stream>>>(esrc, edst, as_b, ad_b, ewb);
    aggregate_kernel<1><<<ngrid, 256, 0, stream>>>(h2, ewb, row_ptr, esrc, b2, nullptr, nullptr, out);
}

// Round 9
// 299.147 us; speedup vs baseline: 2.0780x; 1.0338x over previous
//
#include <hip/hip_runtime.h>
#include <hip/hip_bf16.h>
#include <math.h>

#define N_NODES 50000
#define N_EDGESX 800000
#define E_TOT   (N_EDGESX + N_NODES)
#define IN_C 128
#define HID_C 256
#define OUT_C 128
#define NEG_SLOPE 0.2f

// bucketed counting sort params
#define NPB   100                         // nodes per bucket
#define NBUCK ((N_NODES + NPB - 1) / NPB) // 500
#define BCAP  2560                        // max edges per bucket (mean ~1700)
#define EPB   4096                        // edges per binA block
#define NABLK ((E_TOT + EPB - 1) / EPB)   // 208

typedef __attribute__((ext_vector_type(8))) short short8;
typedef __attribute__((ext_vector_type(4))) float floatx4;
typedef __attribute__((ext_vector_type(2))) float floatx2;

__device__ __forceinline__ float bf2f(short s) {
    unsigned u = ((unsigned)(unsigned short)s) << 16;
    float f; __builtin_memcpy(&f, &u, 4); return f;
}
__device__ __forceinline__ short f2bf(float f) {   // RNE
    unsigned u; __builtin_memcpy(&u, &f, 4);
    unsigned r = (u + 0x7FFFu + ((u >> 16) & 1u)) >> 16;
    return (short)r;
}

// ---------------- projected attention vectors: p[k] = sum_n W[k][n]*a[n] ----------------
template<int KROWS, int NCOLS>
__global__ __launch_bounds__(256)
void gemv_p_kernel(const float* __restrict__ W, const float* __restrict__ a_s,
                   const float* __restrict__ a_d, float* __restrict__ ps, float* __restrict__ pd) {
    int t = threadIdx.x;
    int k = t & (KROWS - 1);
    const float* av = (t < KROWS) ? a_s : a_d;
    float* pv = (t < KROWS) ? ps : pd;
    const float* row = W + (size_t)k * NCOLS;
    float s = 0.f;
    for (int n = 0; n < NCOLS; ++n) s += row[n] * av[n];
    pv[k] = s;
}

// ---------------- alpha1 from x + x->bf16 split (fused, one x pass) ----------------
__global__ __launch_bounds__(256)
void alpha_x_kernel(const float* __restrict__ x, const float* __restrict__ ps,
                    const float* __restrict__ pd, float* __restrict__ as_out,
                    float* __restrict__ ad_out, short* __restrict__ xb) {
    int gt = blockIdx.x * blockDim.x + threadIdx.x;
    int node = gt >> 6, lane = gt & 63;
    if (node >= N_NODES) return;
    floatx2 xv = *(const floatx2*)&x[(size_t)node * IN_C + lane * 2];
    floatx2 s2 = *(const floatx2*)&ps[lane * 2];
    floatx2 d2 = *(const floatx2*)&pd[lane * 2];
    float s = xv[0] * s2[0] + xv[1] * s2[1];
    float d = xv[0] * d2[0] + xv[1] * d2[1];
    unsigned pack = (unsigned)(unsigned short)f2bf(xv[0]) | ((unsigned)(unsigned short)f2bf(xv[1]) << 16);
    *(unsigned*)&xb[(size_t)node * IN_C + lane * 2] = pack;
    #pragma unroll
    for (int off = 32; off; off >>= 1) {
        s += __shfl_down(s, off);
        d += __shfl_down(d, off);
    }
    if (lane == 0) { as_out[node] = s; ad_out[node] = d; }
}

// ---------------- bucketed CSR build ----------------
// stage entry: packed (li<<17 | s), li = d % NPB (<128), s < 2^17
__global__ __launch_bounds__(256)
void binA_kernel(const int* __restrict__ src, const int* __restrict__ dst,
                 int* __restrict__ bcnt, int* __restrict__ stage) {
    __shared__ int hist[NBUCK];
    __shared__ int base[NBUCK];
    for (int b = threadIdx.x; b < NBUCK; b += 256) hist[b] = 0;
    __syncthreads();
    int e0 = blockIdx.x * EPB;
    int e1 = min(e0 + EPB, E_TOT);
    for (int i = e0 + threadIdx.x; i < e1; i += 256) {
        int d = (i < N_EDGESX) ? dst[i] : (i - N_EDGESX);
        atomicAdd(&hist[d / NPB], 1);
    }
    __syncthreads();
    for (int b = threadIdx.x; b < NBUCK; b += 256) {
        int c = hist[b];
        base[b] = c ? atomicAdd(&bcnt[b], c) : 0;
        hist[b] = 0;
    }
    __syncthreads();
    for (int i = e0 + threadIdx.x; i < e1; i += 256) {
        int s, d;
        if (i < N_EDGESX) { s = src[i]; d = dst[i]; }
        else { s = i - N_EDGESX; d = s; }
        int b = d / NPB;
        int off = base[b] + atomicAdd(&hist[b], 1);
        if (off < BCAP) stage[(size_t)b * BCAP + off] = ((d - b * NPB) << 17) | s;
    }
}

// B: per-bucket per-node counts (LDS), coalesced cnt writes
__global__ __launch_bounds__(128)
void bucket_count_kernel(const int* __restrict__ bcnt, const int* __restrict__ stage,
                         int* __restrict__ cnt) {
    __shared__ int lc[NPB];
    int b = blockIdx.x;
    for (int t = threadIdx.x; t < NPB; t += 128) lc[t] = 0;
    __syncthreads();
    int n = min(bcnt[b], BCAP);
    const int* sp = stage + (size_t)b * BCAP;
    for (int i = threadIdx.x; i < n; i += 128)
        atomicAdd(&lc[sp[i] >> 17], 1);
    __syncthreads();
    int nb = b * NPB;
    for (int t = threadIdx.x; t < NPB; t += 128)
        if (nb + t < N_NODES) cnt[nb + t] = lc[t];
}

// C: scatter esrc via LDS cursors + fused layer-1 edge logits
__global__ __launch_bounds__(128)
void bucket_scatter_kernel(const int* __restrict__ bcnt, const int* __restrict__ stage,
                           const int* __restrict__ row_ptr, const float* __restrict__ as_in,
                           const float* __restrict__ ad_in, int* __restrict__ esrc,
                           float* __restrict__ ew) {
    __shared__ int cur[NPB];
    __shared__ float adl[NPB];
    int b = blockIdx.x;
    int nb = b * NPB;
    for (int t = threadIdx.x; t < NPB; t += 128) {
        int node = nb + t;
        cur[t] = (node < N_NODES) ? row_ptr[node] : 0;
        adl[t] = (node < N_NODES) ? ad_in[node] : 0.f;
    }
    __syncthreads();
    int n = min(bcnt[b], BCAP);
    const int* sp = stage + (size_t)b * BCAP;
    for (int i = threadIdx.x; i < n; i += 128) {
        int v = sp[i];
        int s = v & 0x1FFFF;
        int li = v >> 17;
        int pos = atomicAdd(&cur[li], 1);
        esrc[pos] = s;
        float e = as_in[s] + adl[li];
        ew[pos] = e > 0.f ? e : NEG_SLOPE * e;
    }
}

#define NBLK ((N_NODES + 1023) / 1024)   // 49

__global__ __launch_bounds__(1024)
void scan_a_kernel(const int* __restrict__ cnt, int* __restrict__ row_ptr, int* __restrict__ bsum) {
    __shared__ int buf[1024];
    int tid = threadIdx.x;
    int idx = blockIdx.x * 1024 + tid;
    int v = (idx < N_NODES) ? cnt[idx] : 0;
    buf[tid] = v;
    __syncthreads();
    for (int off = 1; off < 1024; off <<= 1) {
        int t = (tid >= off) ? buf[tid - off] : 0;
        __syncthreads();
        buf[tid] += t;
        __syncthreads();
    }
    if (idx < N_NODES) row_ptr[idx] = buf[tid] - v;
    if (tid == 1023) bsum[blockIdx.x] = buf[1023];
}

__global__ void scan_b_kernel(int* __restrict__ bsum, int* __restrict__ row_ptr) {
    int lane = threadIdx.x;   // 64
    int v = (lane < NBLK) ? bsum[lane] : 0;
    int s = v;
    #pragma unroll
    for (int off = 1; off < 64; off <<= 1) {
        int t = __shfl_up(s, off);
        if (lane >= off) s += t;
    }
    if (lane < NBLK) bsum[lane] = s - v;
    if (lane == 63) row_ptr[N_NODES] = s;
}

__global__ __launch_bounds__(1024)
void scan_c_kernel(int* __restrict__ row_ptr, const int* __restrict__ bsum) {
    int idx = blockIdx.x * 1024 + threadIdx.x;
    if (idx < N_NODES) row_ptr[idx] += bsum[blockIdx.x];
}

// edst from row_ptr (coalesced contiguous-range writes)
__global__ __launch_bounds__(256)
void fill_edst_kernel(const int* __restrict__ row_ptr, int* __restrict__ edst) {
    int gt = blockIdx.x * blockDim.x + threadIdx.x;
    int node = gt >> 6, lane = gt & 63;
    if (node >= N_NODES) return;
    int beg = row_ptr[node], end = row_ptr[node + 1];
    for (int i = beg + lane; i < end; i += 64) edst[i] = node;
}

// ---------------- per-edge logits for layer 2 ----------------
__global__ void ew_kernel(const int* __restrict__ esrc, const int* __restrict__ edst,
                          const float* __restrict__ as_in, const float* __restrict__ ad_in,
                          float* __restrict__ ew) {
    int i = blockIdx.x * blockDim.x + threadIdx.x;
    if (i >= E_TOT) return;
    float e = as_in[esrc[i]] + ad_in[edst[i]];
    ew[i] = e > 0.f ? e : NEG_SLOPE * e;
}

// ---------------- W[K][N] -> Wt hi/lo [N][K] ----------------
__global__ void splitT_kernel(const float* __restrict__ W, short* __restrict__ th,
                              short* __restrict__ tl, int K, int N) {
    int i = blockIdx.x * blockDim.x + threadIdx.x;
    if (i >= K * N) return;
    int k = i / N, n = i - k * N;
    float f = W[i];
    short hb = f2bf(f);
    th[n * K + k] = hb;
    tl[n * K + k] = f2bf(f - bf2f(hb));
}

// ---------------- split-bf16 MFMA GEMM ----------------
// C = A[M,K] @ (Bh+Bl)[K,N], Bt stored [N][K]. BM=128, BN=64, 4 waves.
// HASALO: A has a low half (Al) -> 3 MFMA passes, else 2.
// OUTMODE 1: plain bf16 -> C0.  OUTMODE 2: relu(v+bias[gc]) -> bf16 C0.
template<int K, int HASALO, int OUTMODE>
__global__ __launch_bounds__(256)
void gemm_mfma(const short* __restrict__ Ah, const short* __restrict__ Al,
               const short* __restrict__ Bth, const short* __restrict__ Btl,
               int N, const float* __restrict__ bias, short* __restrict__ C0) {
    __shared__ short Ah_s[128][40];
    __shared__ short Al_s[HASALO ? 128 : 1][HASALO ? 40 : 1];
    __shared__ short Bh_s[64][40];
    __shared__ short Bl_s[64][40];
    int tid = threadIdx.x;
    int lane = tid & 63, wave = tid >> 6;
    int wr = wave >> 1, wc = wave & 1;
    int bm = blockIdx.y * 128, bn = blockIdx.x * 64;
    int l15 = lane & 15, kf = (lane >> 4) * 8;

    floatx4 acc[4][2];
    #pragma unroll
    for (int i = 0; i < 4; ++i)
        #pragma unroll
        for (int j = 0; j < 2; ++j) acc[i][j] = (floatx4){0.f, 0.f, 0.f, 0.f};

    int arow = tid >> 1, ac0 = (tid & 1) * 16;
    int brow = tid >> 2, bc0 = (tid & 3) * 8;
    int agm = bm + arow;
    bool aval = agm < N_NODES;

    for (int k0 = 0; k0 < K; k0 += 32) {
        short8 va0 = {0,0,0,0,0,0,0,0}, va1 = va0;
        if (aval) {
            const short* pa = Ah + (size_t)agm * K + k0 + ac0;
            va0 = *(const short8*)pa; va1 = *(const short8*)(pa + 8);
        }
        *(short8*)&Ah_s[arow][ac0]     = va0;
        *(short8*)&Ah_s[arow][ac0 + 8] = va1;
        if (HASALO) {
            short8 vl0 = {0,0,0,0,0,0,0,0}, vl1 = vl0;
            if (aval) {
                const short* pl = Al + (size_t)agm * K + k0 + ac0;
                vl0 = *(const short8*)pl; vl1 = *(const short8*)(pl + 8);
            }
            *(short8*)&Al_s[arow][ac0]     = vl0;
            *(short8*)&Al_s[arow][ac0 + 8] = vl1;
        }
        {
            const short* pb = Bth + (size_t)(bn + brow) * K + k0 + bc0;
            *(short8*)&Bh_s[brow][bc0] = *(const short8*)pb;
            const short* pb2 = Btl + (size_t)(bn + brow) * K + k0 + bc0;
            *(short8*)&Bl_s[brow][bc0] = *(const short8*)pb2;
        }
        __syncthreads();
        short8 afh[4], bfh[2], bfl[2];
        #pragma unroll
        for (int mr = 0; mr < 4; ++mr) {
            int r = wr * 64 + mr * 16 + l15;
            afh[mr] = *(const short8*)&Ah_s[r][kf];
        }
        #pragma unroll
        for (int nr = 0; nr < 2; ++nr) {
            int c = wc * 32 + nr * 16 + l15;
            bfh[nr] = *(const short8*)&Bh_s[c][kf];
            bfl[nr] = *(const short8*)&Bl_s[c][kf];
        }
        #pragma unroll
        for (int mr = 0; mr < 4; ++mr)
            #pragma unroll
            for (int nr = 0; nr < 2; ++nr) {
                acc[mr][nr] = __builtin_amdgcn_mfma_f32_16x16x32_bf16(afh[mr], bfh[nr], acc[mr][nr], 0, 0, 0);
                acc[mr][nr] = __builtin_amdgcn_mfma_f32_16x16x32_bf16(afh[mr], bfl[nr], acc[mr][nr], 0, 0, 0);
            }
        if (HASALO) {
            short8 afl[4];
            #pragma unroll
            for (int mr = 0; mr < 4; ++mr) {
                int r = wr * 64 + mr * 16 + l15;
                afl[mr] = *(const short8*)&Al_s[r][kf];
            }
            #pragma unroll
            for (int mr = 0; mr < 4; ++mr)
                #pragma unroll
                for (int nr = 0; nr < 2; ++nr)
                    acc[mr][nr] = __builtin_amdgcn_mfma_f32_16x16x32_bf16(afl[mr], bfh[nr], acc[mr][nr], 0, 0, 0);
        }
        __syncthreads();
    }
    float bv[2];
    if (OUTMODE == 2) {
        #pragma unroll
        for (int nr = 0; nr < 2; ++nr) bv[nr] = bias[bn + wc * 32 + nr * 16 + l15];
    }
    #pragma unroll
    for (int mr = 0; mr < 4; ++mr) {
        #pragma unroll
        for (int reg = 0; reg < 4; ++reg) {
            int gr = bm + wr * 64 + mr * 16 + (lane >> 4) * 4 + reg;
            if (gr < N_NODES) {
                #pragma unroll
                for (int nr = 0; nr < 2; ++nr) {
                    int gc = bn + wc * 32 + nr * 16 + l15;
                    float v = acc[mr][nr][reg];
                    if (OUTMODE == 2) v = fmaxf(v + bv[nr], 0.f);
                    C0[(size_t)gr * N + gc] = f2bf(v);
                }
            }
        }
    }
}

// ---------------- alpha2 from h2 (bf16) ----------------
__global__ __launch_bounds__(256)
void alpha_bf16_128(const short* __restrict__ h, const float* __restrict__ a_src,
                    const float* __restrict__ a_dst, float* __restrict__ as_out,
                    float* __restrict__ ad_out) {
    int gt = blockIdx.x * blockDim.x + threadIdx.x;
    int node = gt >> 6, lane = gt & 63;
    if (node >= N_NODES) return;
    unsigned u = *(const unsigned*)&h[(size_t)node * OUT_C + lane * 2];
    float v0 = bf2f((short)(u & 0xFFFFu));
    float v1 = bf2f((short)(u >> 16));
    floatx2 as2 = *(const floatx2*)&a_src[lane * 2];
    floatx2 ad2 = *(const floatx2*)&a_dst[lane * 2];
    float s = v0 * as2[0] + v1 * as2[1];
    float d = v0 * ad2[0] + v1 * ad2[1];
    #pragma unroll
    for (int off = 32; off; off >>= 1) {
        s += __shfl_down(s, off);
        d += __shfl_down(d, off);
    }
    if (lane == 0) { as_out[node] = s; ad_out[node] = d; }
}

// ---------------- fused segment softmax + aggregate (F=128 bf16 rows) ----------------
// One wave/node: online (max,sum); gather 4x16-lane groups, 4x unrolled -> 16 rows in flight.
// OUT==0: hi/lo bf16 out. OUT==1: fp32 out + bias (final).
template<int OUT>
__global__ __launch_bounds__(256)
void aggregate_kernel(const short* __restrict__ h, const float* __restrict__ ew,
                      const int* __restrict__ row_ptr, const int* __restrict__ esrc,
                      const float* __restrict__ bias,
                      short* __restrict__ o_hi, short* __restrict__ o_lo,
                      float* __restrict__ o_f32) {
    int gt = blockIdx.x * blockDim.x + threadIdx.x;
    int node = gt >> 6, lane = gt & 63;
    if (node >= N_NODES) return;
    int beg = row_ptr[node], end = row_ptr[node + 1];

    float ml = -1e30f, zl = 0.f;
    for (int i = beg + lane; i < end; i += 64) {
        float e = ew[i];
        float mn = fmaxf(ml, e);
        zl = zl * __expf(ml - mn) + __expf(e - mn);
        ml = mn;
    }
    #pragma unroll
    for (int off = 32; off; off >>= 1) {
        float mo = __shfl_xor(ml, off);
        float zo = __shfl_xor(zl, off);
        float mn = fmaxf(ml, mo);
        zl = zl * __expf(ml - mn) + zo * __expf(mo - mn);
        ml = mn;
    }
    float m = ml;
    float inv_z = 1.f / zl;

    int grp = lane >> 4, l = lane & 15;
    float acc[8] = {};
    int i = beg;
    for (; i + 16 <= end; i += 16) {
        int e0 = i + grp, e1 = e0 + 4, e2 = e0 + 8, e3 = e0 + 12;
        int s0 = esrc[e0], s1 = esrc[e1], s2 = esrc[e2], s3 = esrc[e3];
        float w0 = __expf(ew[e0] - m) * inv_z;
        float w1 = __expf(ew[e1] - m) * inv_z;
        float w2 = __expf(ew[e2] - m) * inv_z;
        float w3 = __expf(ew[e3] - m) * inv_z;
        short8 hv0 = *(const short8*)&h[(size_t)s0 * 128 + l * 8];
        short8 hv1 = *(const short8*)&h[(size_t)s1 * 128 + l * 8];
        short8 hv2 = *(const short8*)&h[(size_t)s2 * 128 + l * 8];
        short8 hv3 = *(const short8*)&h[(size_t)s3 * 128 + l * 8];
        #pragma unroll
        for (int j = 0; j < 8; ++j) acc[j] += w0 * bf2f(hv0[j]);
        #pragma unroll
        for (int j = 0; j < 8; ++j) acc[j] += w1 * bf2f(hv1[j]);
        #pragma unroll
        for (int j = 0; j < 8; ++j) acc[j] += w2 * bf2f(hv2[j]);
        #pragma unroll
        for (int j = 0; j < 8; ++j) acc[j] += w3 * bf2f(hv3[j]);
    }
    for (; i < end; i += 4) {
        int e = i + grp;
        bool v = e < end;
        int s = esrc[v ? e : beg];
        float w = v ? __expf(ew[e] - m) * inv_z : 0.f;
        short8 hv = *(const short8*)&h[(size_t)s * 128 + l * 8];
        #pragma unroll
        for (int j = 0; j < 8; ++j) acc[j] += w * bf2f(hv[j]);
    }
    #pragma unroll
    for (int j = 0; j < 8; ++j) {
        acc[j] += __shfl_xor(acc[j], 16);
        acc[j] += __shfl_xor(acc[j], 32);
    }

    if (lane < 16) {
        if (OUT == 0) {
            short8 oh, ol;
            #pragma unroll
            for (int j = 0; j < 8; ++j) {
                short hb = f2bf(acc[j]);
                oh[j] = hb;
                ol[j] = f2bf(acc[j] - bf2f(hb));
            }
            *(short8*)&o_hi[(size_t)node * 128 + l * 8] = oh;
            *(short8*)&o_lo[(size_t)node * 128 + l * 8] = ol;
        } else {
            const float* brow = &bias[l * 8];
            floatx4 o0, o1;
            #pragma unroll
            for (int j = 0; j < 4; ++j) {
                o0[j] = acc[j] + brow[j];
                o1[j] = acc[j + 4] + brow[j + 4];
            }
            float* orow = &o_f32[(size_t)node * 128 + l * 8];
            *(floatx4*)orow = o0;
            *(floatx4*)(orow + 4) = o1;
        }
    }
}

// ---------------- launch ----------------
extern "C" void kernel_launch(void* const* d_in, const int* in_sizes, int n_in,
                              void* d_out, int out_size, void* d_ws, size_t ws_size,
                              hipStream_t stream) {
    const float* x   = (const float*)d_in[0];
    const int*   ei  = (const int*)d_in[1];
    const float* W1  = (const float*)d_in[2];
    const float* a1s = (const float*)d_in[3];
    const float* a1d = (const float*)d_in[4];
    const float* b1  = (const float*)d_in[5];
    const float* W2  = (const float*)d_in[6];
    const float* a2s = (const float*)d_in[7];
    const float* a2d = (const float*)d_in[8];
    const float* b2  = (const float*)d_in[9];
    float* out = (float*)d_out;

    const int* e_src = ei;
    const int* e_dst = ei + N_EDGESX;

    char* ws = (char*)d_ws;
    const size_t OFF_XB    = 0;             // bf16 [N][128]
    const size_t OFF_UH    = 12800000;
    const size_t OFF_UL    = 25600000;
    const size_t OFF_G1H   = 38400000;      // bf16 [N][256]
    const size_t OFF_H2    = 64000000;      // bf16 [N][128]
    const size_t OFF_W1TH  = 76800000;
    const size_t OFF_W1TL  = 76865536;
    const size_t OFF_W2TH  = 76931072;
    const size_t OFF_W2TL  = 76996608;
    const size_t OFF_P1S   = 77062144;
    const size_t OFF_P1D   = 77062656;
    const size_t OFF_AS    = 77063168;
    const size_t OFF_AD    = 77263360;
    const size_t OFF_RP    = 77463552;
    const size_t OFF_CNT   = 77664000;
    const size_t OFF_BSUM  = 77864192;
    const size_t OFF_BCNT  = 77864448;      // NBUCK ints
    const size_t OFF_ESRC  = 77866496;
    const size_t OFF_EDST  = 81266496;
    const size_t OFF_EW    = 84666496;
    const size_t OFF_STAGE = 88066496;      // int [NBUCK][BCAP] = 5.12 MB

    short* xb   = (short*)(ws + OFF_XB);
    short* uh   = (short*)(ws + OFF_UH);
    short* ul   = (short*)(ws + OFF_UL);
    short* g1h  = (short*)(ws + OFF_G1H);
    short* h2   = (short*)(ws + OFF_H2);
    short* w1th = (short*)(ws + OFF_W1TH);
    short* w1tl = (short*)(ws + OFF_W1TL);
    short* w2th = (short*)(ws + OFF_W2TH);
    short* w2tl = (short*)(ws + OFF_W2TL);
    float* p1s  = (float*)(ws + OFF_P1S);
    float* p1d  = (float*)(ws + OFF_P1D);
    float* as_b = (float*)(ws + OFF_AS);
    float* ad_b = (float*)(ws + OFF_AD);
    int* row_ptr = (int*)(ws + OFF_RP);
    int* cnt     = (int*)(ws + OFF_CNT);
    int* bsum    = (int*)(ws + OFF_BSUM);
    int* bcnt    = (int*)(ws + OFF_BCNT);
    int* esrc    = (int*)(ws + OFF_ESRC);
    int* edst    = (int*)(ws + OFF_EDST);
    float* ewb   = (float*)(ws + OFF_EW);
    int* stage   = (int*)(ws + OFF_STAGE);

    int egrid = (E_TOT + 255) / 256;
    int ngrid = (N_NODES * 64 + 255) / 256;

    // --- alpha1 (from x) + xb split ---
    gemv_p_kernel<IN_C, HID_C><<<1, 256, 0, stream>>>(W1, a1s, a1d, p1s, p1d);
    alpha_x_kernel<<<ngrid, 256, 0, stream>>>(x, p1s, p1d, as_b, ad_b, xb);

    // --- bucketed CSR build ---
    hipMemsetAsync(bcnt, 0, NBUCK * sizeof(int), stream);
    binA_kernel<<<NABLK, 256, 0, stream>>>(e_src, e_dst, bcnt, stage);
    bucket_count_kernel<<<NBUCK, 128, 0, stream>>>(bcnt, stage, cnt);
    scan_a_kernel<<<NBLK, 1024, 0, stream>>>(cnt, row_ptr, bsum);
    scan_b_kernel<<<1, 64, 0, stream>>>(bsum, row_ptr);
    scan_c_kernel<<<NBLK, 1024, 0, stream>>>(row_ptr, bsum);
    bucket_scatter_kernel<<<NBUCK, 128, 0, stream>>>(bcnt, stage, row_ptr, as_b, ad_b, esrc, ewb);
    fill_edst_kernel<<<ngrid, 256, 0, stream>>>(row_ptr, edst);

    // --- weight splits ---
    splitT_kernel<<<(IN_C * HID_C + 255) / 256, 256, 0, stream>>>(W1, w1th, w1tl, IN_C, HID_C);
    splitT_kernel<<<(HID_C * OUT_C + 255) / 256, 256, 0, stream>>>(W2, w2th, w2tl, HID_C, OUT_C);

    // --- layer 1: aggregate x, then transform ---
    aggregate_kernel<0><<<ngrid, 256, 0, stream>>>(xb, ewb, row_ptr, esrc, nullptr, uh, ul, nullptr);
    gemm_mfma<IN_C, 1, 2><<<dim3(HID_C / 64, (N_NODES + 127) / 128), 256, 0, stream>>>(
        uh, ul, w1th, w1tl, HID_C, b1, g1h);

    // --- layer 2: transform, then aggregate ---
    gemm_mfma<HID_C, 0, 1><<<dim3(OUT_C / 64, (N_NODES + 127) / 128), 256, 0, stream>>>(
        g1h, nullptr, w2th, w2tl, OUT_C, nullptr, h2);
    alpha_bf16_128<<<ngrid, 256, 0, stream>>>(h2, a2s, a2d, as_b, ad_b);
    ew_kernel<<<egrid, 256, 0, stream>>>(esrc, edst, as_b, ad_b, ewb);
    aggregate_kernel<1><<<ngrid, 256, 0, stream>>>(h2, ewb, row_ptr, esrc, b2, nullptr, nullptr, out);
}